// Round 7
// baseline (135.859 us; speedup 1.0000x reference)
//
#include <hip/hip_runtime.h>
#include <stdint.h>

typedef unsigned long long u64;
typedef unsigned int u32;
typedef unsigned char u8;

#define NB 8
#define NA 76725
#define NC 80
#define NCH 84
#define PRE_K 200
#define MAXPC 100
#define MAXDET 100
#define F4_PER_IMG (NA * 21u)   // 1,611,225 float4 per image

#define T0 0.93f                // exact gate: sigmoid > 0.93
#define XCUT 2.58f              // raw-logit prefilter (logit(0.93)=2.5867)
#define BLKX 256                // scan blocks per image
#define SPAN (BLKX * 256u)      // 65536 float4 per grid step
#define NSTEP 24                // 24*SPAN = 1,572,864 <= F4_PER_IMG
#define LCAP 24                 // per-(block,class) slot cap (P(overflow)~0)
#define CAP2 512                // k_nms sort size
#define CAPF 2048               // k_final sort size (headroom)

// ---------- helpers ----------

__device__ __forceinline__ float sigmoid_ref(float x) {
    // match jax.nn.sigmoid = 1/(1+exp(-x)) in fp32 (no fast-math approx)
    return 1.0f / (1.0f + expf(-x));
}

// Decode one box exactly like the reference (fp32 ops, no fma contraction;
// anchor dims in double like the python host math, then cast to f32).
__device__ void decode_box(float4 d, int a, float4* box, float* areaOut) {
    int lvl, off, fw, stride;
    if (a < 57600)      { lvl = 0; off = 0;     fw = 80; stride = 8;   }
    else if (a < 72000) { lvl = 1; off = 57600; fw = 40; stride = 16;  }
    else if (a < 75600) { lvl = 2; off = 72000; fw = 20; stride = 32;  }
    else if (a < 76500) { lvl = 3; off = 75600; fw = 10; stride = 64;  }
    else                { lvl = 4; off = 76500; fw = 5;  stride = 128; }
    int idx  = a - off;
    int k    = idx % 9;
    int cell = idx / 9;
    int row = cell / fw, col = cell - row * fw;
    float cx = __fmul_rn((float)col + 0.5f, (float)stride);
    float cy = __fmul_rn((float)row + 0.5f, (float)stride);
    int ri = k / 3, si = k - ri * 3;
    double r    = (ri == 0) ? 0.5 : ((ri == 1) ? 1.0 : 2.0);
    double side = (double)(32 << lvl);
    double area = side * side;
    double h = sqrt(area / r);
    double w = area / h;
    double s = exp2((double)si / 3.0);
    float aw = (float)(s * w);
    float ah = (float)(s * h);
    float b0 = __fmul_rn(d.x, 0.1f);
    float b1 = __fmul_rn(d.y, 0.1f);
    float b2 = __fmul_rn(d.z, 0.2f);
    float b3 = __fmul_rn(d.w, 0.2f);
    float ux = __fadd_rn(__fmul_rn(b0, aw), cx);
    float uy = __fadd_rn(__fmul_rn(b1, ah), cy);
    float wx = __fmul_rn(expf(b2), aw);
    float wy = __fmul_rn(expf(b3), ah);
    float hx = __fmul_rn(wx, 0.5f);
    float hy = __fmul_rn(wy, 0.5f);
    float x1 = __fsub_rn(ux, hx), y1 = __fsub_rn(uy, hy);
    float x2 = __fadd_rn(ux, hx), y2 = __fadd_rn(uy, hy);
    *box = make_float4(x1, y1, x2, y2);
    *areaOut = __fmul_rn(__fsub_rn(x2, x1), __fsub_rn(y2, y1));
}

// descending bitonic sort of n (power of 2) u64 keys in LDS
__device__ __forceinline__ void bitonic_desc(u64* keys, u32 n) {
    for (u32 k = 2; k <= n; k <<= 1) {
        for (u32 j = k >> 1; j > 0; j >>= 1) {
            for (u32 i = threadIdx.x; i < n; i += blockDim.x) {
                u32 ixj = i ^ j;
                if (ixj > i) {
                    u64 x = keys[i], y = keys[ixj];
                    if (((i & k) == 0u) ? (x < y) : (x > y)) {
                        keys[i] = y; keys[ixj] = x;
                    }
                }
            }
            __syncthreads();
        }
    }
}

// ---------- kernel 1: streaming scan, class-major flush (no global atomics) ----------

__device__ __forceinline__ void scan4(float4 v, u32 idx,
                                      u32* lhist, u64 (*llist)[LCAP]) {
    u32 a  = idx / 21u;
    u32 c4 = idx - a * 21u;
    if (c4 == 0u) return;                        // box channels
    float m = fmaxf(fmaxf(v.x, v.y), fmaxf(v.z, v.w));
    if (m <= XCUT) return;
    u32 cb = c4 * 4u - 4u;
    float vv[4] = {v.x, v.y, v.z, v.w};
#pragma unroll
    for (int q = 0; q < 4; ++q) {
        if (vv[q] > XCUT) {
            float sig = sigmoid_ref(vv[q]);
            if (sig > T0) {
                u32 c = cb + (u32)q;
                u64 key = ((u64)__float_as_uint(sig) << 32) | (u64)(~a);
                u32 p = atomicAdd(&lhist[c], 1u);
                if (p < LCAP) llist[c][p] = key;
                // overflow (never in practice): unclamped count triggers repair
            }
        }
    }
}

__global__ __launch_bounds__(256, 4) void k_scan(const float4* __restrict__ p4,
                                                 u64* __restrict__ seg,
                                                 u32* __restrict__ cntT) {
    __shared__ u32 lhist[NC];
    __shared__ u64 llist[NC][LCAP];
    u32 b = blockIdx.y, x = blockIdx.x;
    for (u32 c = threadIdx.x; c < NC; c += 256u) lhist[c] = 0u;
    __syncthreads();

    const float4* base = p4 + (u64)b * F4_PER_IMG;
    u32 i0 = x * 256u + threadIdx.x;
#pragma unroll 1
    for (int s = 0; s < NSTEP; s += 4) {
        u32 ia = i0 + (u32)s * SPAN;
        float4 v0 = base[ia];
        float4 v1 = base[ia + SPAN];
        float4 v2 = base[ia + 2u * SPAN];
        float4 v3 = base[ia + 3u * SPAN];
        scan4(v0, ia,            lhist, llist);
        scan4(v1, ia + SPAN,     lhist, llist);
        scan4(v2, ia + 2u*SPAN,  lhist, llist);
        scan4(v3, ia + 3u*SPAN,  lhist, llist);
    }
    {
        u32 it = i0 + (u32)NSTEP * SPAN;
        if (it < F4_PER_IMG) scan4(base[it], it, lhist, llist);
    }
    __syncthreads();

    // class-major flush: block x owns slot row [ (b*NC+c)*BLKX + x ] * LCAP
    if (threadIdx.x < NC) {
        u32 c = threadIdx.x;
        u32 n = lhist[c];
        u32 m = n < LCAP ? n : (u32)LCAP;
        u64* o = seg + ((u64)(b * NC + c) * BLKX + x) * LCAP;
        for (u32 j = 0; j < m; ++j) o[j] = llist[c][j];
        cntT[(b * NC + c) * BLKX + x] = n;
    }
}

// ---------- kernel 2: coalesced gather + sort + NMS (parallel Jacobi sweep) ----------

__global__ __launch_bounds__(256) void k_nms(const float* __restrict__ pred,
                                             const u64* __restrict__ seg,
                                             const u32* __restrict__ cntT,
                                             float* __restrict__ sc2,
                                             float* __restrict__ bb2) {
    int bc = blockIdx.x;
    int b = bc / NC, c = bc % NC;
    __shared__ u64 keys[CAP2];
    __shared__ u32 gc[BLKX];
    __shared__ u32 gflag;
    __shared__ u32 gtot;
    __shared__ float4 box[PRE_K];
    __shared__ float area[PRE_K];
    __shared__ u32 suppT[PRE_K][7];   // suppT[j][w]: bits of suppressors i<j
    __shared__ u32 validw[7];
    __shared__ u32 keepw[7];
    __shared__ u32 nkeep[7];
    __shared__ u32 chg;
    __shared__ u64 red[256];

    if (threadIdx.x == 0) gflag = 0u;
    __syncthreads();

    // coalesced: 256 consecutive u32 counts for this (b,c)
    u32 m_c = 0;
    {
        u32 n = cntT[(u64)bc * BLKX + threadIdx.x];
        if (n > (u32)LCAP) atomicOr(&gflag, 1u);
        m_c = n < LCAP ? n : (u32)LCAP;
        gc[threadIdx.x] = m_c;
    }
    __syncthreads();
    for (u32 d = 1; d < BLKX; d <<= 1) {
        u32 v = 0;
        if (threadIdx.x >= d) v = gc[threadIdx.x - d];
        __syncthreads();
        gc[threadIdx.x] += v;
        __syncthreads();
    }
    if (threadIdx.x == 0) gtot = gc[BLKX - 1];
    __syncthreads();
    u32 total = gtot;
    bool repaired = (gflag != 0u) || (total < (u32)PRE_K) || (total > (u32)CAP2);

    if (!repaired) {
        {
            u32 dst = gc[threadIdx.x] - m_c;
            const u64* src = seg + ((u64)bc * BLKX + threadIdx.x) * LCAP;
            for (u32 j = 0; j < m_c; ++j) keys[dst + j] = src[j];
        }
        for (u32 i = threadIdx.x; i < CAP2; i += blockDim.x)
            if (i >= total) keys[i] = 0ull;
        __syncthreads();
        bitonic_desc(keys, CAP2);
    } else {
        // exact argmax-extraction top-200 (never taken for this input; exact)
        u64 cur = ~0ull;
        for (int k = 0; k < PRE_K; ++k) {
            u64 loc = 0;
            for (int a = threadIdx.x; a < NA; a += blockDim.x) {
                float xx = pred[((long)b * NA + a) * NCH + 4 + c];
                float sg = sigmoid_ref(xx);
                u64 key  = ((u64)__float_as_uint(sg) << 32) | (u64)(~(u32)a);
                if (key < cur && key > loc) loc = key;
            }
            red[threadIdx.x] = loc;
            __syncthreads();
            for (int s = 128; s > 0; s >>= 1) {
                if (threadIdx.x < (u32)s) {
                    if (red[threadIdx.x + s] > red[threadIdx.x])
                        red[threadIdx.x] = red[threadIdx.x + s];
                }
                __syncthreads();
            }
            cur = red[0];
            if (threadIdx.x == 0) keys[k] = cur;
            __syncthreads();
        }
        for (u32 i = PRE_K + threadIdx.x; i < CAP2; i += blockDim.x) keys[i] = 0ull;
        __syncthreads();
    }

    for (int i = threadIdx.x; i < PRE_K * 7; i += blockDim.x) suppT[i / 7][i % 7] = 0u;
    if (threadIdx.x < 7) validw[threadIdx.x] = 0u;
    __syncthreads();

    if (threadIdx.x < PRE_K) {
        int r   = threadIdx.x;
        u64 key = keys[r];
        float sig = __uint_as_float((u32)(key >> 32));
        int a = (int)(~(u32)key);
        float4 bx = make_float4(0.f, 0.f, 0.f, 0.f);
        float ar = 0.f;
        if (sig > 0.05f) {  // valid = sc > CONF_THR
            float4 dd = *(const float4*)(pred + ((long)b * NA + a) * NCH);
            decode_box(dd, a, &bx, &ar);
            atomicOr(&validw[r >> 5], 1u << (r & 31));
        }
        box[r] = bx; area[r] = ar;
    }
    __syncthreads();

    // suppression bitmask, TRANSPOSED: bit i of suppT[j] set for i<j with IoU>0.5
    for (int p = threadIdx.x; p < PRE_K * PRE_K; p += blockDim.x) {
        int i  = p / PRE_K;
        int jx = p - i * PRE_K;
        if (jx > i) {
            float4 bi = box[i], bj = box[jx];
            float ltx = fmaxf(bi.x, bj.x), lty = fmaxf(bi.y, bj.y);
            float rbx = fminf(bi.z, bj.z), rby = fminf(bi.w, bj.w);
            float wx = fmaxf(__fsub_rn(rbx, ltx), 0.f);
            float wy = fmaxf(__fsub_rn(rby, lty), 0.f);
            float inter = __fmul_rn(wx, wy);
            float den = __fadd_rn(__fsub_rn(__fadd_rn(area[i], area[jx]), inter), 1e-8f);
            float iou = __fdiv_rn(inter, den);
            if (iou > 0.5f) atomicOr(&suppT[jx][i >> 5], 1u << (i & 31));
        }
    }
    if (threadIdx.x < 7) keepw[threadIdx.x] = 0u;  // placeholder, set below
    __syncthreads();
    if (threadIdx.x < 7) keepw[threadIdx.x] = validw[threadIdx.x];
    __syncthreads();

    // parallel Jacobi fixpoint == greedy NMS (unique solution of the
    // forward recurrence; converges in <= chain depth <= PRE_K sweeps)
    for (int t = 0; t < PRE_K; ++t) {
        if (threadIdx.x < 7) nkeep[threadIdx.x] = 0u;
        if (threadIdx.x == 0) chg = 0u;
        __syncthreads();
        if (threadIdx.x < PRE_K) {
            int j = threadIdx.x;
            u32 sup = 0;
#pragma unroll
            for (int w = 0; w < 7; ++w) sup |= keepw[w] & suppT[j][w];
            u32 ob = (keepw[j >> 5] >> (j & 31)) & 1u;
            u32 vb = (validw[j >> 5] >> (j & 31)) & 1u;
            u32 nb = vb & (sup == 0u ? 1u : 0u);
            if (nb) atomicOr(&nkeep[j >> 5], 1u << (j & 31));
            if (nb != ob) chg = 1u;
        }
        __syncthreads();
        if (threadIdx.x < 7) keepw[threadIdx.x] = nkeep[threadIdx.x];
        __syncthreads();
        if (chg == 0u) break;
    }

    // full write of per-class top-100 (zero-fill; no memset dependency)
    int kept = 0;
#pragma unroll
    for (int w = 0; w < 7; ++w) kept += __popc(keepw[w]);
    if (kept > MAXPC) kept = MAXPC;

    if (threadIdx.x >= (u32)kept && threadIdx.x < MAXPC) {
        int pos = threadIdx.x;
        sc2[bc * MAXPC + pos] = 0.f;
        float* o = bb2 + ((long)bc * MAXPC + pos) * 4;
        o[0] = 0.f; o[1] = 0.f; o[2] = 0.f; o[3] = 0.f;
    }
    if (threadIdx.x < PRE_K) {
        int r = threadIdx.x;
        if ((keepw[r >> 5] >> (r & 31)) & 1u) {
            int pos = 0;
            for (int w = 0; w < (r >> 5); ++w) pos += __popc(keepw[w]);
            pos += __popc(keepw[r >> 5] & ((1u << (r & 31)) - 1u));
            if (pos < MAXPC) {
                u64 key = keys[r];
                float sig = __uint_as_float((u32)(key >> 32));
                sc2[bc * MAXPC + pos] = sig;
                float4 bx = box[r];
                float* o = bb2 + ((long)bc * MAXPC + pos) * 4;
                o[0] = bx.x; o[1] = bx.y; o[2] = bx.z; o[3] = bx.w;
            }
        }
    }
}

// ---------- kernel 3: per-image final top-100 + full output write ----------

__global__ __launch_bounds__(1024) void k_final(const float* __restrict__ sc2,
                                                const float* __restrict__ bb2,
                                                float* __restrict__ out) {
    int b = blockIdx.x;
    __shared__ u32 hist[256];
    __shared__ u64 keys[CAPF];
    __shared__ u32 cnt_s;
    __shared__ int t_s;
    for (int i = threadIdx.x; i < 256; i += blockDim.x) hist[i] = 0u;
    if (threadIdx.x == 0) cnt_s = 0u;
    __syncthreads();

    const float* s_b = sc2 + b * (NC * MAXPC);
    for (int f = threadIdx.x; f < NC * MAXPC; f += blockDim.x) {
        float s = s_b[f];
        if (s > 0.f) {
            int bin = (int)(s * 256.f); if (bin > 255) bin = 255;
            atomicAdd(&hist[bin], 1u);
        }
    }
    __syncthreads();
    if (threadIdx.x == 0) {
        u32 cum = 0; int t = 0;
        for (int bin = 255; bin >= 0; --bin) {
            cum += hist[bin];
            if (cum >= (u32)MAXDET) { t = bin; break; }
        }
        t_s = t;
    }
    __syncthreads();
    int t = t_s;
    for (int f = threadIdx.x; f < NC * MAXPC; f += blockDim.x) {
        float s = s_b[f];
        if (s > 0.f) {
            int bin = (int)(s * 256.f); if (bin > 255) bin = 255;
            if (bin >= t) {
                u32 pos = atomicAdd(&cnt_s, 1u);
                if (pos < CAPF)
                    keys[pos] = ((u64)__float_as_uint(s) << 32) | (u64)(~(u32)f);
            }
        }
    }
    __syncthreads();
    u32 g = cnt_s; if (g > (u32)CAPF) g = CAPF;
    for (int i = threadIdx.x; i < CAPF; i += blockDim.x)
        if (i >= (int)g) keys[i] = 0ull;
    __syncthreads();

    bitonic_desc(keys, CAPF);

    if (threadIdx.x < MAXDET) {
        int r = threadIdx.x;
        u64 key = keys[r];
        u32 hi = (u32)(key >> 32);
        float s = 0.f, cf = 0.f;
        float bx0 = 0.f, bx1 = 0.f, bx2 = 0.f, bx3 = 0.f;
        if (hi != 0u) {
            s = __uint_as_float(hi);
            int f = (int)(~(u32)key);
            int c = f / MAXPC, jj = f - c * MAXPC;
            const float* bsrc = bb2 + ((long)(b * NC + c) * MAXPC + jj) * 4;
            bx0 = bsrc[0]; bx1 = bsrc[1]; bx2 = bsrc[2]; bx3 = bsrc[3];
            cf = (float)c;
        }
        float* ob = out + ((long)b * MAXDET + r) * 4;
        ob[0] = bx0; ob[1] = bx1; ob[2] = bx2; ob[3] = bx3;
        out[NB * MAXDET * 4 + b * MAXDET + r] = s;
        out[NB * MAXDET * 4 + NB * MAXDET + b * MAXDET + r] = cf;
    }
    __syncthreads();
    if (threadIdx.x == 0) {
        int nv = 0;
        for (int r = 0; r < MAXDET; ++r)
            if ((u32)(keys[r] >> 32) != 0u) ++nv;
        out[NB * MAXDET * 4 + 2 * NB * MAXDET + b] = (float)nv;
    }
}

// ---------- launcher ----------

extern "C" void kernel_launch(void* const* d_in, const int* in_sizes, int n_in,
                              void* d_out, int out_size, void* d_ws, size_t ws_size,
                              hipStream_t stream) {
    // inputs: images [8,640,640,3] (unused), predictions [8,76725,84]
    const float* pred = (const float*)d_in[1];
    if (n_in >= 2 && in_sizes[0] == NB * NA * NCH) pred = (const float*)d_in[0];

    char* ws = (char*)d_ws;
    const long BCN = (long)NB * NC;                    // 640
    u64* seg   = (u64*)ws;                             // 640*256*24*8 = 31,457,280 B
    char* p    = ws + BCN * BLKX * LCAP * 8;
    u32* cntT  = (u32*)p;            p += BCN * BLKX * 4;              // 655,360 B
    float* sc2 = (float*)p;          p += BCN * MAXPC * 4;             // 256,000 B
    float* bb2 = (float*)p;                                            // 1,024,000 B

    k_scan <<<dim3(BLKX, NB), 256, 0, stream>>>((const float4*)pred, seg, cntT);
    k_nms  <<<dim3(NB * NC),  256, 0, stream>>>(pred, seg, cntT, sc2, bb2);
    k_final<<<dim3(NB),      1024, 0, stream>>>(sc2, bb2, (float*)d_out);
}

// Round 8
// 123.161 us; speedup vs baseline: 1.1031x; 1.1031x over previous
//
#include <hip/hip_runtime.h>
#include <stdint.h>

typedef unsigned long long u64;
typedef unsigned int u32;
typedef unsigned char u8;

#define NB 8
#define NA 76725
#define NC 80
#define NCH 84
#define PRE_K 200
#define MAXPC 100
#define MAXDET 100
#define F4_PER_IMG (NA * 21u)   // 1,611,225 float4 per image

#define T0 0.93f                // exact gate: sigmoid > 0.93
#define XCUT 2.58f              // raw-logit prefilter (logit(0.93)=2.5867)
#define BLKX 256                // scan blocks per image
#define SPAN (BLKX * 256u)      // 65536 float4 per grid step
#define NSTEP 24                // 24*SPAN = 1,572,864 <= F4_PER_IMG
#define LCAP 24                 // per-(block,class) slot cap (P(overflow)~0)
#define CAP2 512                // k_nms sort size
#define CAPF 2048               // k_final max sort size

// ---------- helpers ----------

__device__ __forceinline__ float sigmoid_ref(float x) {
    // match jax.nn.sigmoid = 1/(1+exp(-x)) in fp32 (no fast-math approx)
    return 1.0f / (1.0f + expf(-x));
}

// Decode one box exactly like the reference (fp32 ops, no fma contraction;
// anchor dims in double like the python host math, then cast to f32).
__device__ void decode_box(float4 d, int a, float4* box, float* areaOut) {
    int lvl, off, fw, stride;
    if (a < 57600)      { lvl = 0; off = 0;     fw = 80; stride = 8;   }
    else if (a < 72000) { lvl = 1; off = 57600; fw = 40; stride = 16;  }
    else if (a < 75600) { lvl = 2; off = 72000; fw = 20; stride = 32;  }
    else if (a < 76500) { lvl = 3; off = 75600; fw = 10; stride = 64;  }
    else                { lvl = 4; off = 76500; fw = 5;  stride = 128; }
    int idx  = a - off;
    int k    = idx % 9;
    int cell = idx / 9;
    int row = cell / fw, col = cell - row * fw;
    float cx = __fmul_rn((float)col + 0.5f, (float)stride);
    float cy = __fmul_rn((float)row + 0.5f, (float)stride);
    int ri = k / 3, si = k - ri * 3;
    double r    = (ri == 0) ? 0.5 : ((ri == 1) ? 1.0 : 2.0);
    double side = (double)(32 << lvl);
    double area = side * side;
    double h = sqrt(area / r);
    double w = area / h;
    double s = exp2((double)si / 3.0);
    float aw = (float)(s * w);
    float ah = (float)(s * h);
    float b0 = __fmul_rn(d.x, 0.1f);
    float b1 = __fmul_rn(d.y, 0.1f);
    float b2 = __fmul_rn(d.z, 0.2f);
    float b3 = __fmul_rn(d.w, 0.2f);
    float ux = __fadd_rn(__fmul_rn(b0, aw), cx);
    float uy = __fadd_rn(__fmul_rn(b1, ah), cy);
    float wx = __fmul_rn(expf(b2), aw);
    float wy = __fmul_rn(expf(b3), ah);
    float hx = __fmul_rn(wx, 0.5f);
    float hy = __fmul_rn(wy, 0.5f);
    float x1 = __fsub_rn(ux, hx), y1 = __fsub_rn(uy, hy);
    float x2 = __fadd_rn(ux, hx), y2 = __fadd_rn(uy, hy);
    *box = make_float4(x1, y1, x2, y2);
    *areaOut = __fmul_rn(__fsub_rn(x2, x1), __fsub_rn(y2, y1));
}

// descending bitonic sort of n (power of 2) u64 keys in LDS
__device__ __forceinline__ void bitonic_desc(u64* keys, u32 n) {
    for (u32 k = 2; k <= n; k <<= 1) {
        for (u32 j = k >> 1; j > 0; j >>= 1) {
            for (u32 i = threadIdx.x; i < n; i += blockDim.x) {
                u32 ixj = i ^ j;
                if (ixj > i) {
                    u64 x = keys[i], y = keys[ixj];
                    if (((i & k) == 0u) ? (x < y) : (x > y)) {
                        keys[i] = y; keys[ixj] = x;
                    }
                }
            }
            __syncthreads();
        }
    }
}

// ---------- kernel 1: streaming scan, class-major flush (no global atomics) ----------

__device__ __forceinline__ void scan4(float4 v, u32 idx,
                                      u32* lhist, u64 (*llist)[LCAP]) {
    u32 a  = idx / 21u;
    u32 c4 = idx - a * 21u;
    if (c4 == 0u) return;                        // box channels
    float m = fmaxf(fmaxf(v.x, v.y), fmaxf(v.z, v.w));
    if (m <= XCUT) return;
    u32 cb = c4 * 4u - 4u;
    float vv[4] = {v.x, v.y, v.z, v.w};
#pragma unroll
    for (int q = 0; q < 4; ++q) {
        if (vv[q] > XCUT) {
            float sig = sigmoid_ref(vv[q]);
            if (sig > T0) {
                u32 c = cb + (u32)q;
                u64 key = ((u64)__float_as_uint(sig) << 32) | (u64)(~a);
                u32 p = atomicAdd(&lhist[c], 1u);
                if (p < LCAP) llist[c][p] = key;
                // overflow (never in practice): unclamped count triggers repair
            }
        }
    }
}

__global__ __launch_bounds__(256, 4) void k_scan(const float4* __restrict__ p4,
                                                 u64* __restrict__ seg,
                                                 u32* __restrict__ cntT) {
    __shared__ u32 lhist[NC];
    __shared__ u64 llist[NC][LCAP];
    u32 b = blockIdx.y, x = blockIdx.x;
    for (u32 c = threadIdx.x; c < NC; c += 256u) lhist[c] = 0u;
    __syncthreads();

    const float4* base = p4 + (u64)b * F4_PER_IMG;
    u32 i0 = x * 256u + threadIdx.x;
#pragma unroll 1
    for (int s = 0; s < NSTEP; s += 4) {
        u32 ia = i0 + (u32)s * SPAN;
        float4 v0 = base[ia];
        float4 v1 = base[ia + SPAN];
        float4 v2 = base[ia + 2u * SPAN];
        float4 v3 = base[ia + 3u * SPAN];
        scan4(v0, ia,            lhist, llist);
        scan4(v1, ia + SPAN,     lhist, llist);
        scan4(v2, ia + 2u*SPAN,  lhist, llist);
        scan4(v3, ia + 3u*SPAN,  lhist, llist);
    }
    {
        u32 it = i0 + (u32)NSTEP * SPAN;
        if (it < F4_PER_IMG) scan4(base[it], it, lhist, llist);
    }
    __syncthreads();

    // class-major flush: block x owns slot row [ (b*NC+c)*BLKX + x ] * LCAP
    if (threadIdx.x < NC) {
        u32 c = threadIdx.x;
        u32 n = lhist[c];
        u32 m = n < LCAP ? n : (u32)LCAP;
        u64* o = seg + ((u64)(b * NC + c) * BLKX + x) * LCAP;
        for (u32 j = 0; j < m; ++j) o[j] = llist[c][j];
        cntT[(b * NC + c) * BLKX + x] = n;
    }
}

// ---------- kernel 2: coalesced gather + sort + NMS (parallel Jacobi sweep) ----------

__global__ __launch_bounds__(256) void k_nms(const float* __restrict__ pred,
                                             const u64* __restrict__ seg,
                                             const u32* __restrict__ cntT,
                                             float* __restrict__ sc2,
                                             float* __restrict__ bb2) {
    int bc = blockIdx.x;
    int b = bc / NC, c = bc % NC;
    __shared__ u64 keys[CAP2];
    __shared__ u32 gc[BLKX];
    __shared__ u32 gflag;
    __shared__ u32 gtot;
    __shared__ float4 box[PRE_K];
    __shared__ float area[PRE_K];
    __shared__ u32 suppT[PRE_K][7];   // suppT[j][w]: bits of suppressors i<j
    __shared__ u32 validw[7];
    __shared__ u32 keepw[7];
    __shared__ u32 nkeep[7];
    __shared__ u32 chg;
    __shared__ u64 red[256];

    if (threadIdx.x == 0) gflag = 0u;
    __syncthreads();

    // coalesced: 256 consecutive u32 counts for this (b,c)
    u32 m_c = 0;
    {
        u32 n = cntT[(u64)bc * BLKX + threadIdx.x];
        if (n > (u32)LCAP) atomicOr(&gflag, 1u);
        m_c = n < LCAP ? n : (u32)LCAP;
        gc[threadIdx.x] = m_c;
    }
    __syncthreads();
    for (u32 d = 1; d < BLKX; d <<= 1) {
        u32 v = 0;
        if (threadIdx.x >= d) v = gc[threadIdx.x - d];
        __syncthreads();
        gc[threadIdx.x] += v;
        __syncthreads();
    }
    if (threadIdx.x == 0) gtot = gc[BLKX - 1];
    __syncthreads();
    u32 total = gtot;
    bool repaired = (gflag != 0u) || (total < (u32)PRE_K) || (total > (u32)CAP2);

    if (!repaired) {
        {
            u32 dst = gc[threadIdx.x] - m_c;
            const u64* src = seg + ((u64)bc * BLKX + threadIdx.x) * LCAP;
            for (u32 j = 0; j < m_c; ++j) keys[dst + j] = src[j];
        }
        for (u32 i = threadIdx.x; i < CAP2; i += blockDim.x)
            if (i >= total) keys[i] = 0ull;
        __syncthreads();
        bitonic_desc(keys, CAP2);
    } else {
        // exact argmax-extraction top-200 (never taken for this input; exact)
        u64 cur = ~0ull;
        for (int k = 0; k < PRE_K; ++k) {
            u64 loc = 0;
            for (int a = threadIdx.x; a < NA; a += blockDim.x) {
                float xx = pred[((long)b * NA + a) * NCH + 4 + c];
                float sg = sigmoid_ref(xx);
                u64 key  = ((u64)__float_as_uint(sg) << 32) | (u64)(~(u32)a);
                if (key < cur && key > loc) loc = key;
            }
            red[threadIdx.x] = loc;
            __syncthreads();
            for (int s = 128; s > 0; s >>= 1) {
                if (threadIdx.x < (u32)s) {
                    if (red[threadIdx.x + s] > red[threadIdx.x])
                        red[threadIdx.x] = red[threadIdx.x + s];
                }
                __syncthreads();
            }
            cur = red[0];
            if (threadIdx.x == 0) keys[k] = cur;
            __syncthreads();
        }
        for (u32 i = PRE_K + threadIdx.x; i < CAP2; i += blockDim.x) keys[i] = 0ull;
        __syncthreads();
    }

    for (int i = threadIdx.x; i < PRE_K * 7; i += blockDim.x) suppT[i / 7][i % 7] = 0u;
    if (threadIdx.x < 7) validw[threadIdx.x] = 0u;
    __syncthreads();

    if (threadIdx.x < PRE_K) {
        int r   = threadIdx.x;
        u64 key = keys[r];
        float sig = __uint_as_float((u32)(key >> 32));
        int a = (int)(~(u32)key);
        float4 bx = make_float4(0.f, 0.f, 0.f, 0.f);
        float ar = 0.f;
        if (sig > 0.05f) {  // valid = sc > CONF_THR
            float4 dd = *(const float4*)(pred + ((long)b * NA + a) * NCH);
            decode_box(dd, a, &bx, &ar);
            atomicOr(&validw[r >> 5], 1u << (r & 31));
        }
        box[r] = bx; area[r] = ar;
    }
    __syncthreads();

    // suppression bitmask, TRANSPOSED: bit i of suppT[j] set for i<j with IoU>0.5
    for (int p = threadIdx.x; p < PRE_K * PRE_K; p += blockDim.x) {
        int i  = p / PRE_K;
        int jx = p - i * PRE_K;
        if (jx > i) {
            float4 bi = box[i], bj = box[jx];
            float ltx = fmaxf(bi.x, bj.x), lty = fmaxf(bi.y, bj.y);
            float rbx = fminf(bi.z, bj.z), rby = fminf(bi.w, bj.w);
            float wx = fmaxf(__fsub_rn(rbx, ltx), 0.f);
            float wy = fmaxf(__fsub_rn(rby, lty), 0.f);
            float inter = __fmul_rn(wx, wy);
            float den = __fadd_rn(__fsub_rn(__fadd_rn(area[i], area[jx]), inter), 1e-8f);
            float iou = __fdiv_rn(inter, den);
            if (iou > 0.5f) atomicOr(&suppT[jx][i >> 5], 1u << (i & 31));
        }
    }
    __syncthreads();
    if (threadIdx.x < 7) keepw[threadIdx.x] = validw[threadIdx.x];
    __syncthreads();

    // parallel Jacobi fixpoint == greedy NMS (unique solution of the
    // forward recurrence; stabilizes prefix-by-prefix, <= PRE_K sweeps)
    for (int t = 0; t < PRE_K; ++t) {
        if (threadIdx.x < 7) nkeep[threadIdx.x] = 0u;
        if (threadIdx.x == 0) chg = 0u;
        __syncthreads();
        if (threadIdx.x < PRE_K) {
            int j = threadIdx.x;
            u32 sup = 0;
#pragma unroll
            for (int w = 0; w < 7; ++w) sup |= keepw[w] & suppT[j][w];
            u32 ob = (keepw[j >> 5] >> (j & 31)) & 1u;
            u32 vb = (validw[j >> 5] >> (j & 31)) & 1u;
            u32 nb = vb & (sup == 0u ? 1u : 0u);
            if (nb) atomicOr(&nkeep[j >> 5], 1u << (j & 31));
            if (nb != ob) chg = 1u;
        }
        __syncthreads();
        if (threadIdx.x < 7) keepw[threadIdx.x] = nkeep[threadIdx.x];
        __syncthreads();
        if (chg == 0u) break;
    }

    // full write of per-class top-100 (zero-fill; no memset dependency)
    int kept = 0;
#pragma unroll
    for (int w = 0; w < 7; ++w) kept += __popc(keepw[w]);
    if (kept > MAXPC) kept = MAXPC;

    if (threadIdx.x >= (u32)kept && threadIdx.x < MAXPC) {
        int pos = threadIdx.x;
        sc2[bc * MAXPC + pos] = 0.f;
        float* o = bb2 + ((long)bc * MAXPC + pos) * 4;
        o[0] = 0.f; o[1] = 0.f; o[2] = 0.f; o[3] = 0.f;
    }
    if (threadIdx.x < PRE_K) {
        int r = threadIdx.x;
        if ((keepw[r >> 5] >> (r & 31)) & 1u) {
            int pos = 0;
            for (int w = 0; w < (r >> 5); ++w) pos += __popc(keepw[w]);
            pos += __popc(keepw[r >> 5] & ((1u << (r & 31)) - 1u));
            if (pos < MAXPC) {
                u64 key = keys[r];
                float sig = __uint_as_float((u32)(key >> 32));
                sc2[bc * MAXPC + pos] = sig;
                float4 bx = box[r];
                float* o = bb2 + ((long)bc * MAXPC + pos) * 4;
                o[0] = bx.x; o[1] = bx.y; o[2] = bx.z; o[3] = bx.w;
            }
        }
    }
}

// ---------- kernel 3: per-image final top-100, fully parallel ----------

__global__ __launch_bounds__(1024) void k_final(const float* __restrict__ sc2,
                                                const float* __restrict__ bb2,
                                                float* __restrict__ out) {
    int b = blockIdx.x;
    __shared__ u32 hist[256];
    __shared__ u32 sfx[256];
    __shared__ u64 keys[CAPF];
    __shared__ u32 cnt_s;
    __shared__ int t_s;
    __shared__ u64 red[1024];

    for (int i = threadIdx.x; i < 256; i += blockDim.x) hist[i] = 0u;
    if (threadIdx.x == 0) { cnt_s = 0u; t_s = 0; }
    __syncthreads();

    const float* s_b = sc2 + b * (NC * MAXPC);
    for (int f = threadIdx.x; f < NC * MAXPC; f += blockDim.x) {
        float s = s_b[f];
        if (s > 0.f) {
            int bin = (int)(s * 256.f); if (bin > 255) bin = 255;
            atomicAdd(&hist[bin], 1u);
        }
    }
    __syncthreads();

    // parallel suffix-sum: sfx[bin] = sum_{b'>=bin} hist[b']
    if (threadIdx.x < 256) sfx[threadIdx.x] = hist[threadIdx.x];
    __syncthreads();
    for (u32 d = 1; d < 256u; d <<= 1) {
        u32 v = 0;
        if (threadIdx.x < 256u && threadIdx.x + d < 256u) v = sfx[threadIdx.x + d];
        __syncthreads();
        if (threadIdx.x < 256u) sfx[threadIdx.x] += v;
        __syncthreads();
    }
    // t = largest bin with sfx[bin] >= MAXDET (sfx nonincreasing in bin); else 0
    if (threadIdx.x < 256) {
        bool ge = sfx[threadIdx.x] >= (u32)MAXDET;
        bool nlt = (threadIdx.x == 255) || (sfx[threadIdx.x + 1] < (u32)MAXDET);
        if (ge && nlt) t_s = (int)threadIdx.x;
    }
    __syncthreads();
    int t = t_s;

    // gather candidates with bin >= t
    for (int f = threadIdx.x; f < NC * MAXPC; f += blockDim.x) {
        float s = s_b[f];
        if (s > 0.f) {
            int bin = (int)(s * 256.f); if (bin > 255) bin = 255;
            if (bin >= t) {
                u32 pos = atomicAdd(&cnt_s, 1u);
                if (pos < CAPF)
                    keys[pos] = ((u64)__float_as_uint(s) << 32) | (u64)(~(u32)f);
            }
        }
    }
    __syncthreads();
    u32 g = cnt_s;

    if (g <= (u32)CAPF) {
        u32 n = (g <= 1024u) ? 1024u : (u32)CAPF;
        for (u32 i = threadIdx.x; i < n; i += blockDim.x)
            if (i >= g) keys[i] = 0ull;
        __syncthreads();
        bitonic_desc(keys, n);
    } else {
        // exact fallback (never for this input): 100 rounds of block argmax
        __syncthreads();
        u64 cur = ~0ull;
        for (int k = 0; k < MAXDET; ++k) {
            u64 loc = 0;
            for (int f = threadIdx.x; f < NC * MAXPC; f += blockDim.x) {
                float s = s_b[f];
                if (s > 0.f) {
                    u64 key = ((u64)__float_as_uint(s) << 32) | (u64)(~(u32)f);
                    if (key < cur && key > loc) loc = key;
                }
            }
            red[threadIdx.x] = loc;
            __syncthreads();
            for (int st = 512; st > 0; st >>= 1) {
                if (threadIdx.x < (u32)st) {
                    if (red[threadIdx.x + st] > red[threadIdx.x])
                        red[threadIdx.x] = red[threadIdx.x + st];
                }
                __syncthreads();
            }
            cur = red[0];
            if (threadIdx.x == 0) keys[k] = cur;
            __syncthreads();
        }
        // g for nv: count nonzero among first MAXDET
        if (threadIdx.x == 0) {
            u32 nv = 0;
            for (int r = 0; r < MAXDET; ++r) if (keys[r] != 0ull) ++nv;
            cnt_s = nv;
        }
        __syncthreads();
        g = cnt_s;
    }

    if (threadIdx.x < MAXDET) {
        int r = threadIdx.x;
        u64 key = keys[r];
        u32 hi = (u32)(key >> 32);
        float s = 0.f, cf = 0.f;
        float bx0 = 0.f, bx1 = 0.f, bx2 = 0.f, bx3 = 0.f;
        if (hi != 0u) {
            s = __uint_as_float(hi);
            int f = (int)(~(u32)key);
            int c = f / MAXPC, jj = f - c * MAXPC;
            const float* bsrc = bb2 + ((long)(b * NC + c) * MAXPC + jj) * 4;
            bx0 = bsrc[0]; bx1 = bsrc[1]; bx2 = bsrc[2]; bx3 = bsrc[3];
            cf = (float)c;
        }
        float* ob = out + ((long)b * MAXDET + r) * 4;
        ob[0] = bx0; ob[1] = bx1; ob[2] = bx2; ob[3] = bx3;
        out[NB * MAXDET * 4 + b * MAXDET + r] = s;
        out[NB * MAXDET * 4 + NB * MAXDET + b * MAXDET + r] = cf;
    }
    if (threadIdx.x == 0) {
        // nv = min(g, MAXDET): gathered set is exactly the positives above t,
        // a superset of the positive top-100 (t=0 when fewer than 100 positives)
        u32 nv = g < (u32)MAXDET ? g : (u32)MAXDET;
        out[NB * MAXDET * 4 + 2 * NB * MAXDET + b] = (float)nv;
    }
}

// ---------- launcher ----------

extern "C" void kernel_launch(void* const* d_in, const int* in_sizes, int n_in,
                              void* d_out, int out_size, void* d_ws, size_t ws_size,
                              hipStream_t stream) {
    // inputs: images [8,640,640,3] (unused), predictions [8,76725,84]
    const float* pred = (const float*)d_in[1];
    if (n_in >= 2 && in_sizes[0] == NB * NA * NCH) pred = (const float*)d_in[0];

    char* ws = (char*)d_ws;
    const long BCN = (long)NB * NC;                    // 640
    u64* seg   = (u64*)ws;                             // 640*256*24*8 = 31,457,280 B
    char* p    = ws + BCN * BLKX * LCAP * 8;
    u32* cntT  = (u32*)p;            p += BCN * BLKX * 4;              // 655,360 B
    float* sc2 = (float*)p;          p += BCN * MAXPC * 4;             // 256,000 B
    float* bb2 = (float*)p;                                            // 1,024,000 B

    k_scan <<<dim3(BLKX, NB), 256, 0, stream>>>((const float4*)pred, seg, cntT);
    k_nms  <<<dim3(NB * NC),  256, 0, stream>>>(pred, seg, cntT, sc2, bb2);
    k_final<<<dim3(NB),      1024, 0, stream>>>(sc2, bb2, (float*)d_out);
}

// Round 9
// 111.017 us; speedup vs baseline: 1.2238x; 1.1094x over previous
//
#include <hip/hip_runtime.h>
#include <stdint.h>

typedef unsigned long long u64;
typedef unsigned int u32;
typedef unsigned char u8;

#define NB 8
#define NA 76725
#define NC 80
#define NCH 84
#define PRE_K 200
#define MAXPC 100
#define MAXDET 100
#define F4_PER_IMG (NA * 21u)   // 1,611,225 float4 per image

#define T0 0.93f                // exact gate: sigmoid > 0.93
#define XCUT 2.58f              // raw-logit prefilter (logit(0.93)=2.5867)
#define BLKX 256                // scan blocks per image
#define SPAN (BLKX * 256u)      // 65536 float4 per grid step
#define NSTEP 24                // 24*SPAN = 1,572,864 <= F4_PER_IMG
#define LCAP 24                 // per-(block,class) slot cap (P(overflow)~0)
#define CAP2 512                // k_nms max candidates
#define CAPF 2048               // k_final max candidates

// ---------- helpers ----------

__device__ __forceinline__ float sigmoid_ref(float x) {
    // match jax.nn.sigmoid = 1/(1+exp(-x)) in fp32 (no fast-math approx)
    return 1.0f / (1.0f + expf(-x));
}

// Decode one box exactly like the reference (fp32 ops, no fma contraction;
// anchor dims in double like the python host math, then cast to f32).
__device__ void decode_box(float4 d, int a, float4* box, float* areaOut) {
    int lvl, off, fw, stride;
    if (a < 57600)      { lvl = 0; off = 0;     fw = 80; stride = 8;   }
    else if (a < 72000) { lvl = 1; off = 57600; fw = 40; stride = 16;  }
    else if (a < 75600) { lvl = 2; off = 72000; fw = 20; stride = 32;  }
    else if (a < 76500) { lvl = 3; off = 75600; fw = 10; stride = 64;  }
    else                { lvl = 4; off = 76500; fw = 5;  stride = 128; }
    int idx  = a - off;
    int k    = idx % 9;
    int cell = idx / 9;
    int row = cell / fw, col = cell - row * fw;
    float cx = __fmul_rn((float)col + 0.5f, (float)stride);
    float cy = __fmul_rn((float)row + 0.5f, (float)stride);
    int ri = k / 3, si = k - ri * 3;
    double r    = (ri == 0) ? 0.5 : ((ri == 1) ? 1.0 : 2.0);
    double side = (double)(32 << lvl);
    double area = side * side;
    double h = sqrt(area / r);
    double w = area / h;
    double s = exp2((double)si / 3.0);
    float aw = (float)(s * w);
    float ah = (float)(s * h);
    float b0 = __fmul_rn(d.x, 0.1f);
    float b1 = __fmul_rn(d.y, 0.1f);
    float b2 = __fmul_rn(d.z, 0.2f);
    float b3 = __fmul_rn(d.w, 0.2f);
    float ux = __fadd_rn(__fmul_rn(b0, aw), cx);
    float uy = __fadd_rn(__fmul_rn(b1, ah), cy);
    float wx = __fmul_rn(expf(b2), aw);
    float wy = __fmul_rn(expf(b3), ah);
    float hx = __fmul_rn(wx, 0.5f);
    float hy = __fmul_rn(wy, 0.5f);
    float x1 = __fsub_rn(ux, hx), y1 = __fsub_rn(uy, hy);
    float x2 = __fadd_rn(ux, hx), y2 = __fadd_rn(uy, hy);
    *box = make_float4(x1, y1, x2, y2);
    *areaOut = __fmul_rn(__fsub_rn(x2, x1), __fsub_rn(y2, y1));
}

// ---------- kernel 1: streaming scan, class-major flush (no global atomics) ----------

__device__ __forceinline__ void scan4(float4 v, u32 idx,
                                      u32* lhist, u64 (*llist)[LCAP]) {
    u32 a  = idx / 21u;
    u32 c4 = idx - a * 21u;
    if (c4 == 0u) return;                        // box channels
    float m = fmaxf(fmaxf(v.x, v.y), fmaxf(v.z, v.w));
    if (m <= XCUT) return;
    u32 cb = c4 * 4u - 4u;
    float vv[4] = {v.x, v.y, v.z, v.w};
#pragma unroll
    for (int q = 0; q < 4; ++q) {
        if (vv[q] > XCUT) {
            float sig = sigmoid_ref(vv[q]);
            if (sig > T0) {
                u32 c = cb + (u32)q;
                u64 key = ((u64)__float_as_uint(sig) << 32) | (u64)(~a);
                u32 p = atomicAdd(&lhist[c], 1u);
                if (p < LCAP) llist[c][p] = key;
                // overflow (never in practice): unclamped count triggers repair
            }
        }
    }
}

__global__ __launch_bounds__(256, 4) void k_scan(const float4* __restrict__ p4,
                                                 u64* __restrict__ seg,
                                                 u32* __restrict__ cntT) {
    __shared__ u32 lhist[NC];
    __shared__ u64 llist[NC][LCAP];
    u32 b = blockIdx.y, x = blockIdx.x;
    for (u32 c = threadIdx.x; c < NC; c += 256u) lhist[c] = 0u;
    __syncthreads();

    const float4* base = p4 + (u64)b * F4_PER_IMG;
    u32 i0 = x * 256u + threadIdx.x;
#pragma unroll 1
    for (int s = 0; s < NSTEP; s += 4) {
        u32 ia = i0 + (u32)s * SPAN;
        float4 v0 = base[ia];
        float4 v1 = base[ia + SPAN];
        float4 v2 = base[ia + 2u * SPAN];
        float4 v3 = base[ia + 3u * SPAN];
        scan4(v0, ia,            lhist, llist);
        scan4(v1, ia + SPAN,     lhist, llist);
        scan4(v2, ia + 2u*SPAN,  lhist, llist);
        scan4(v3, ia + 3u*SPAN,  lhist, llist);
    }
    {
        u32 it = i0 + (u32)NSTEP * SPAN;
        if (it < F4_PER_IMG) scan4(base[it], it, lhist, llist);
    }
    __syncthreads();

    // class-major flush: block x owns slot row [ (b*NC+c)*BLKX + x ] * LCAP
    if (threadIdx.x < NC) {
        u32 c = threadIdx.x;
        u32 n = lhist[c];
        u32 m = n < LCAP ? n : (u32)LCAP;
        u64* o = seg + ((u64)(b * NC + c) * BLKX + x) * LCAP;
        for (u32 j = 0; j < m; ++j) o[j] = llist[c][j];
        cntT[(b * NC + c) * BLKX + x] = n;
    }
}

// ---------- kernel 2: gather + rank-sort + NMS (ballot Jacobi, reg suppT) ----------

__global__ __launch_bounds__(256) void k_nms(const float* __restrict__ pred,
                                             const u64* __restrict__ seg,
                                             const u32* __restrict__ cntT,
                                             float* __restrict__ sc2,
                                             float* __restrict__ bb2) {
    int bc = blockIdx.x;
    int b = bc / NC, c = bc % NC;
    __shared__ u64 keys[CAP2];        // unsorted gathered candidates
    __shared__ u64 sorted[PRE_K];     // top-200 descending
    __shared__ u32 wsum[4];
    __shared__ u32 oflow[4];
    __shared__ float4 box[PRE_K];
    __shared__ float area[PRE_K];
    __shared__ u32 validw[8];
    __shared__ u32 keepw[8];
    __shared__ u32 chg;
    __shared__ u64 red[256];

    u32 tid = threadIdx.x, lane = tid & 63u, wv = tid >> 6;

    // --- counts: coalesced load + wave-shfl prefix (2 barriers) ---
    u32 n_raw = cntT[(u64)bc * BLKX + tid];
    u32 m_c = n_raw < LCAP ? n_raw : (u32)LCAP;
    u32 v = m_c;
#pragma unroll
    for (u32 d = 1; d < 64u; d <<= 1) {
        u32 t = __shfl_up(v, d, 64);
        if (lane >= d) v += t;
    }
    u64 ob = __ballot(n_raw > (u32)LCAP);
    if (lane == 63u) wsum[wv] = v;
    if (lane == 0u)  oflow[wv] = (ob != 0ull) ? 1u : 0u;
    __syncthreads();
    u32 off = 0;
    for (u32 w = 0; w < wv; ++w) off += wsum[w];
    u32 inc = v + off;                       // inclusive prefix over all 256
    u32 total = wsum[0] + wsum[1] + wsum[2] + wsum[3];
    bool over = (oflow[0] | oflow[1] | oflow[2] | oflow[3]) != 0u;
    bool repaired = over || (total < (u32)PRE_K) || (total > (u32)CAP2);

    if (!repaired) {
        // --- gather (scattered LDS writes, coalesced-ish global reads) ---
        u32 dst = inc - m_c;
        const u64* src = seg + ((u64)bc * BLKX + tid) * LCAP;
        for (u32 j = 0; j < m_c; ++j) keys[dst + j] = src[j];
        __syncthreads();
        // --- rank-sort: rank = #{j: key_j > key_i}; scatter rank<200 ---
        u64 ka = (tid < total) ? keys[tid] : 0ull;
        u64 kb = (tid + 256u < total) ? keys[tid + 256u] : 0ull;
        u32 ra = 0, rb = 0;
        for (u32 j = 0; j < total; ++j) {
            u64 kj = keys[j];                // broadcast read
            ra += (kj > ka) ? 1u : 0u;
            rb += (kj > kb) ? 1u : 0u;
        }
        if (tid < total && ra < (u32)PRE_K) sorted[ra] = ka;
        if (tid + 256u < total && rb < (u32)PRE_K) sorted[rb] = kb;
        __syncthreads();
    } else {
        // exact argmax-extraction top-200 (never taken for this input; exact)
        u64 cur = ~0ull;
        for (int k = 0; k < PRE_K; ++k) {
            u64 loc = 0;
            for (int a = tid; a < NA; a += 256) {
                float xx = pred[((long)b * NA + a) * NCH + 4 + c];
                float sg = sigmoid_ref(xx);
                u64 key  = ((u64)__float_as_uint(sg) << 32) | (u64)(~(u32)a);
                if (key < cur && key > loc) loc = key;
            }
            red[tid] = loc;
            __syncthreads();
            for (int s = 128; s > 0; s >>= 1) {
                if (tid < (u32)s) {
                    if (red[tid + s] > red[tid]) red[tid] = red[tid + s];
                }
                __syncthreads();
            }
            cur = red[0];
            if (tid == 0) sorted[k] = cur;
            __syncthreads();
        }
    }

    // --- decode + validity/keep masks via ballot (1 barrier) ---
    bool val = false;
    float4 mybox = make_float4(0.f, 0.f, 0.f, 0.f);
    float myarea = 0.f;
    if (tid < (u32)PRE_K) {
        u64 key = sorted[tid];
        float sig = __uint_as_float((u32)(key >> 32));
        int a = (int)(~(u32)key);
        if (sig > 0.05f) {  // valid = sc > CONF_THR
            float4 dd = *(const float4*)(pred + ((long)b * NA + a) * NCH);
            decode_box(dd, a, &mybox, &myarea);
            val = true;
        }
        box[tid] = mybox; area[tid] = myarea;
    }
    u64 vbal = __ballot(val);
    if (lane == 0u) {
        validw[2u * wv]      = (u32)vbal;
        validw[2u * wv + 1u] = (u32)(vbal >> 32);
        keepw[2u * wv]       = (u32)vbal;
        keepw[2u * wv + 1u]  = (u32)(vbal >> 32);
    }
    __syncthreads();

    // --- IoU pass: per-thread register suppressor masks (broadcast reads) ---
    u32 rsup[7];
#pragma unroll
    for (int w = 0; w < 7; ++w) {
        u32 m = 0;
        if (val && (u32)(w * 32) < tid) {
            for (int ii = 0; ii < 32; ++ii) {
                int i = w * 32 + ii;
                if ((u32)i < tid) {
                    float4 bi = box[i];
                    float ai = area[i];
                    float ltx = fmaxf(bi.x, mybox.x), lty = fmaxf(bi.y, mybox.y);
                    float rbx = fminf(bi.z, mybox.z), rby = fminf(bi.w, mybox.w);
                    float wx = fmaxf(__fsub_rn(rbx, ltx), 0.f);
                    float wy = fmaxf(__fsub_rn(rby, lty), 0.f);
                    float inter = __fmul_rn(wx, wy);
                    float den = __fadd_rn(__fsub_rn(__fadd_rn(ai, myarea), inter), 1e-8f);
                    float iou = __fdiv_rn(inter, den);
                    if (iou > 0.5f) m |= 1u << ii;
                }
            }
        }
        rsup[w] = m;   // static index (w unrolled)
    }
    __syncthreads();

    // --- Jacobi fixpoint == greedy NMS (ballot writeback, 3 barriers/sweep) ---
    for (int t = 0; t < PRE_K; ++t) {
        if (tid == 0) chg = 0u;
        __syncthreads();
        u32 k0 = keepw[0], k1 = keepw[1], k2 = keepw[2], k3 = keepw[3];
        u32 k4 = keepw[4], k5 = keepw[5], k6 = keepw[6];
        bool nb = false;
        if (val) {
            u32 sup = (k0 & rsup[0]) | (k1 & rsup[1]) | (k2 & rsup[2]) |
                      (k3 & rsup[3]) | (k4 & rsup[4]) | (k5 & rsup[5]) |
                      (k6 & rsup[6]);
            nb = (sup == 0u);
        }
        u64 bal = __ballot(nb);
        u64 oldk = ((u64)keepw[2u * wv + 1u] << 32) | (u64)keepw[2u * wv];
        if (lane == 0u) {
            keepw[2u * wv]      = (u32)bal;
            keepw[2u * wv + 1u] = (u32)(bal >> 32);
            if (bal != oldk) chg = 1u;
        }
        __syncthreads();
        u32 cflag = chg;
        __syncthreads();
        if (cflag == 0u) break;
    }

    // --- write per-class top-100 (full write incl. zeros; no memset dep) ---
    int kept = 0;
#pragma unroll
    for (int w = 0; w < 7; ++w) kept += __popc(keepw[w]);
    if (kept > MAXPC) kept = MAXPC;

    if (tid >= (u32)kept && tid < (u32)MAXPC) {
        int pos = tid;
        sc2[bc * MAXPC + pos] = 0.f;
        float* o = bb2 + ((long)bc * MAXPC + pos) * 4;
        o[0] = 0.f; o[1] = 0.f; o[2] = 0.f; o[3] = 0.f;
    }
    if (tid < (u32)PRE_K) {
        int r = tid;
        if ((keepw[r >> 5] >> (r & 31)) & 1u) {
            int pos = 0;
            for (int w = 0; w < (r >> 5); ++w) pos += __popc(keepw[w]);
            pos += __popc(keepw[r >> 5] & ((1u << (r & 31)) - 1u));
            if (pos < MAXPC) {
                u64 key = sorted[r];
                float sig = __uint_as_float((u32)(key >> 32));
                sc2[bc * MAXPC + pos] = sig;
                float* o = bb2 + ((long)bc * MAXPC + pos) * 4;
                o[0] = mybox.x; o[1] = mybox.y; o[2] = mybox.z; o[3] = mybox.w;
            }
        }
    }
}

// ---------- kernel 3: per-image final top-100, rank-select ----------

__global__ __launch_bounds__(1024) void k_final(const float* __restrict__ sc2,
                                                const float* __restrict__ bb2,
                                                float* __restrict__ out) {
    int b = blockIdx.x;
    __shared__ u32 hist[256];
    __shared__ u32 sfx[256];
    __shared__ u64 keys[CAPF];
    __shared__ u64 top[128];
    __shared__ u32 cnt_s;
    __shared__ int t_s;
    __shared__ u64 red[1024];

    for (int i = threadIdx.x; i < 256; i += blockDim.x) hist[i] = 0u;
    if (threadIdx.x < 128) top[threadIdx.x] = 0ull;
    if (threadIdx.x == 0) { cnt_s = 0u; t_s = 0; }
    __syncthreads();

    const float* s_b = sc2 + b * (NC * MAXPC);
    for (int f = threadIdx.x; f < NC * MAXPC; f += blockDim.x) {
        float s = s_b[f];
        if (s > 0.f) {
            int bin = (int)(s * 256.f); if (bin > 255) bin = 255;
            atomicAdd(&hist[bin], 1u);
        }
    }
    __syncthreads();

    // parallel suffix-sum: sfx[bin] = sum_{b'>=bin} hist[b']
    if (threadIdx.x < 256) sfx[threadIdx.x] = hist[threadIdx.x];
    __syncthreads();
    for (u32 d = 1; d < 256u; d <<= 1) {
        u32 v = 0;
        if (threadIdx.x < 256u && threadIdx.x + d < 256u) v = sfx[threadIdx.x + d];
        __syncthreads();
        if (threadIdx.x < 256u) sfx[threadIdx.x] += v;
        __syncthreads();
    }
    if (threadIdx.x < 256) {
        bool ge = sfx[threadIdx.x] >= (u32)MAXDET;
        bool nlt = (threadIdx.x == 255) || (sfx[threadIdx.x + 1] < (u32)MAXDET);
        if (ge && nlt) t_s = (int)threadIdx.x;
    }
    __syncthreads();
    int t = t_s;

    // gather candidates with bin >= t
    for (int f = threadIdx.x; f < NC * MAXPC; f += blockDim.x) {
        float s = s_b[f];
        if (s > 0.f) {
            int bin = (int)(s * 256.f); if (bin > 255) bin = 255;
            if (bin >= t) {
                u32 pos = atomicAdd(&cnt_s, 1u);
                if (pos < CAPF)
                    keys[pos] = ((u64)__float_as_uint(s) << 32) | (u64)(~(u32)f);
            }
        }
    }
    __syncthreads();
    u32 g = cnt_s;

    if (g <= (u32)CAPF) {
        // rank-select top-100 (keys unique)
        u64 ka = (threadIdx.x < g) ? keys[threadIdx.x] : 0ull;
        u64 kb = (threadIdx.x + 1024u < g) ? keys[threadIdx.x + 1024u] : 0ull;
        u32 ra = 0, rb = 0;
        for (u32 j = 0; j < g; ++j) {
            u64 kj = keys[j];                 // broadcast read
            ra += (kj > ka) ? 1u : 0u;
            rb += (kj > kb) ? 1u : 0u;
        }
        if (threadIdx.x < g && ra < (u32)MAXDET) top[ra] = ka;
        if (threadIdx.x + 1024u < g && rb < (u32)MAXDET) top[rb] = kb;
        __syncthreads();
    } else {
        // exact fallback (never for this input): 100 rounds of block argmax
        u64 cur = ~0ull;
        for (int k = 0; k < MAXDET; ++k) {
            u64 loc = 0;
            for (int f = threadIdx.x; f < NC * MAXPC; f += blockDim.x) {
                float s = s_b[f];
                if (s > 0.f) {
                    u64 key = ((u64)__float_as_uint(s) << 32) | (u64)(~(u32)f);
                    if (key < cur && key > loc) loc = key;
                }
            }
            red[threadIdx.x] = loc;
            __syncthreads();
            for (int st = 512; st > 0; st >>= 1) {
                if (threadIdx.x < (u32)st) {
                    if (red[threadIdx.x + st] > red[threadIdx.x])
                        red[threadIdx.x] = red[threadIdx.x + st];
                }
                __syncthreads();
            }
            cur = red[0];
            if (threadIdx.x == 0) top[k] = cur;
            __syncthreads();
        }
        if (threadIdx.x == 0) {
            u32 nv = 0;
            for (int r = 0; r < MAXDET; ++r) if (top[r] != 0ull) ++nv;
            cnt_s = nv;
        }
        __syncthreads();
        g = cnt_s;
    }

    if (threadIdx.x < MAXDET) {
        int r = threadIdx.x;
        u64 key = top[r];
        u32 hi = (u32)(key >> 32);
        float s = 0.f, cf = 0.f;
        float bx0 = 0.f, bx1 = 0.f, bx2 = 0.f, bx3 = 0.f;
        if (hi != 0u) {
            s = __uint_as_float(hi);
            int f = (int)(~(u32)key);
            int c = f / MAXPC, jj = f - c * MAXPC;
            const float* bsrc = bb2 + ((long)(b * NC + c) * MAXPC + jj) * 4;
            bx0 = bsrc[0]; bx1 = bsrc[1]; bx2 = bsrc[2]; bx3 = bsrc[3];
            cf = (float)c;
        }
        float* ob = out + ((long)b * MAXDET + r) * 4;
        ob[0] = bx0; ob[1] = bx1; ob[2] = bx2; ob[3] = bx3;
        out[NB * MAXDET * 4 + b * MAXDET + r] = s;
        out[NB * MAXDET * 4 + NB * MAXDET + b * MAXDET + r] = cf;
    }
    if (threadIdx.x == 0) {
        // nv = min(g, MAXDET): gathered set = all positives above t, a
        // superset of the positive top-100 (t=0 when fewer than 100 positives)
        u32 nv = g < (u32)MAXDET ? g : (u32)MAXDET;
        out[NB * MAXDET * 4 + 2 * NB * MAXDET + b] = (float)nv;
    }
}

// ---------- launcher ----------

extern "C" void kernel_launch(void* const* d_in, const int* in_sizes, int n_in,
                              void* d_out, int out_size, void* d_ws, size_t ws_size,
                              hipStream_t stream) {
    // inputs: images [8,640,640,3] (unused), predictions [8,76725,84]
    const float* pred = (const float*)d_in[1];
    if (n_in >= 2 && in_sizes[0] == NB * NA * NCH) pred = (const float*)d_in[0];

    char* ws = (char*)d_ws;
    const long BCN = (long)NB * NC;                    // 640
    u64* seg   = (u64*)ws;                             // 640*256*24*8 = 31,457,280 B
    char* p    = ws + BCN * BLKX * LCAP * 8;
    u32* cntT  = (u32*)p;            p += BCN * BLKX * 4;              // 655,360 B
    float* sc2 = (float*)p;          p += BCN * MAXPC * 4;             // 256,000 B
    float* bb2 = (float*)p;                                            // 1,024,000 B

    k_scan <<<dim3(BLKX, NB), 256, 0, stream>>>((const float4*)pred, seg, cntT);
    k_nms  <<<dim3(NB * NC),  256, 0, stream>>>(pred, seg, cntT, sc2, bb2);
    k_final<<<dim3(NB),      1024, 0, stream>>>(sc2, bb2, (float*)d_out);
}

// Round 10
// 110.767 us; speedup vs baseline: 1.2265x; 1.0023x over previous
//
#include <hip/hip_runtime.h>
#include <stdint.h>

typedef unsigned long long u64;
typedef unsigned int u32;
typedef unsigned char u8;

#define NB 8
#define NA 76725
#define NC 80
#define NCH 84
#define PRE_K 200
#define MAXPC 100
#define MAXDET 100
#define F4_PER_IMG (NA * 21u)   // 1,611,225 float4 per image

#define T0 0.93f                // exact gate: sigmoid > 0.93
#define XCUT 2.58f              // raw-logit prefilter (logit(0.93)=2.5867)
#define BLKX 256                // scan blocks per image
#define SPAN (BLKX * 256u)      // 65536 float4 per grid step
#define NSTEP 24                // 24*SPAN = 1,572,864 <= F4_PER_IMG
#define LCAP 24                 // per-(block,class) slot cap (P(overflow)~0)
#define CAP2 512                // k_nms max candidates
#define CAPF 2048               // k_final max candidates

// ---------- helpers ----------

__device__ __forceinline__ float sigmoid_ref(float x) {
    // match jax.nn.sigmoid = 1/(1+exp(-x)) in fp32 (no fast-math approx)
    return 1.0f / (1.0f + expf(-x));
}

// Decode one box exactly like the reference (fp32 ops, no fma contraction;
// anchor dims in double like the python host math, then cast to f32).
__device__ void decode_box(float4 d, int a, float4* box, float* areaOut) {
    int lvl, off, fw, stride;
    if (a < 57600)      { lvl = 0; off = 0;     fw = 80; stride = 8;   }
    else if (a < 72000) { lvl = 1; off = 57600; fw = 40; stride = 16;  }
    else if (a < 75600) { lvl = 2; off = 72000; fw = 20; stride = 32;  }
    else if (a < 76500) { lvl = 3; off = 75600; fw = 10; stride = 64;  }
    else                { lvl = 4; off = 76500; fw = 5;  stride = 128; }
    int idx  = a - off;
    int k    = idx % 9;
    int cell = idx / 9;
    int row = cell / fw, col = cell - row * fw;
    float cx = __fmul_rn((float)col + 0.5f, (float)stride);
    float cy = __fmul_rn((float)row + 0.5f, (float)stride);
    int ri = k / 3, si = k - ri * 3;
    double r    = (ri == 0) ? 0.5 : ((ri == 1) ? 1.0 : 2.0);
    double side = (double)(32 << lvl);
    double area = side * side;
    double h = sqrt(area / r);
    double w = area / h;
    double s = exp2((double)si / 3.0);
    float aw = (float)(s * w);
    float ah = (float)(s * h);
    float b0 = __fmul_rn(d.x, 0.1f);
    float b1 = __fmul_rn(d.y, 0.1f);
    float b2 = __fmul_rn(d.z, 0.2f);
    float b3 = __fmul_rn(d.w, 0.2f);
    float ux = __fadd_rn(__fmul_rn(b0, aw), cx);
    float uy = __fadd_rn(__fmul_rn(b1, ah), cy);
    float wx = __fmul_rn(expf(b2), aw);
    float wy = __fmul_rn(expf(b3), ah);
    float hx = __fmul_rn(wx, 0.5f);
    float hy = __fmul_rn(wy, 0.5f);
    float x1 = __fsub_rn(ux, hx), y1 = __fsub_rn(uy, hy);
    float x2 = __fadd_rn(ux, hx), y2 = __fadd_rn(uy, hy);
    *box = make_float4(x1, y1, x2, y2);
    *areaOut = __fmul_rn(__fsub_rn(x2, x1), __fsub_rn(y2, y1));
}

// ---------- kernel 1: streaming scan, class-major flush (no global atomics) ----------

__device__ __forceinline__ void scan4(float4 v, u32 idx,
                                      u32* lhist, u64 (*llist)[LCAP]) {
    u32 a  = idx / 21u;
    u32 c4 = idx - a * 21u;
    if (c4 == 0u) return;                        // box channels
    float m = fmaxf(fmaxf(v.x, v.y), fmaxf(v.z, v.w));
    if (m <= XCUT) return;
    u32 cb = c4 * 4u - 4u;
    float vv[4] = {v.x, v.y, v.z, v.w};
#pragma unroll
    for (int q = 0; q < 4; ++q) {
        if (vv[q] > XCUT) {
            float sig = sigmoid_ref(vv[q]);
            if (sig > T0) {
                u32 c = cb + (u32)q;
                u64 key = ((u64)__float_as_uint(sig) << 32) | (u64)(~a);
                u32 p = atomicAdd(&lhist[c], 1u);
                if (p < LCAP) llist[c][p] = key;
                // overflow (never in practice): unclamped count triggers repair
            }
        }
    }
}

__global__ __launch_bounds__(256, 4) void k_scan(const float4* __restrict__ p4,
                                                 u64* __restrict__ seg,
                                                 u32* __restrict__ cntT) {
    __shared__ u32 lhist[NC];
    __shared__ u64 llist[NC][LCAP];
    u32 b = blockIdx.y, x = blockIdx.x;
    for (u32 c = threadIdx.x; c < NC; c += 256u) lhist[c] = 0u;
    __syncthreads();

    const float4* base = p4 + (u64)b * F4_PER_IMG;
    u32 i0 = x * 256u + threadIdx.x;
#pragma unroll 1
    for (int s = 0; s < NSTEP; s += 4) {
        u32 ia = i0 + (u32)s * SPAN;
        float4 v0 = base[ia];
        float4 v1 = base[ia + SPAN];
        float4 v2 = base[ia + 2u * SPAN];
        float4 v3 = base[ia + 3u * SPAN];
        scan4(v0, ia,            lhist, llist);
        scan4(v1, ia + SPAN,     lhist, llist);
        scan4(v2, ia + 2u*SPAN,  lhist, llist);
        scan4(v3, ia + 3u*SPAN,  lhist, llist);
    }
    {
        u32 it = i0 + (u32)NSTEP * SPAN;
        if (it < F4_PER_IMG) scan4(base[it], it, lhist, llist);
    }
    __syncthreads();

    // class-major flush: block x owns slot row [ (b*NC+c)*BLKX + x ] * LCAP
    if (threadIdx.x < NC) {
        u32 c = threadIdx.x;
        u32 n = lhist[c];
        u32 m = n < LCAP ? n : (u32)LCAP;
        u64* o = seg + ((u64)(b * NC + c) * BLKX + x) * LCAP;
        for (u32 j = 0; j < m; ++j) o[j] = llist[c][j];
        cntT[(b * NC + c) * BLKX + x] = n;
    }
}

// ---------- kernel 2: gather + rank-sort + NMS (wave-0 register Jacobi) ----------

__global__ __launch_bounds__(256) void k_nms(const float* __restrict__ pred,
                                             const u64* __restrict__ seg,
                                             const u32* __restrict__ cntT,
                                             float* __restrict__ sc2,
                                             float* __restrict__ bb2) {
    int bc = blockIdx.x;
    int b = bc / NC, c = bc % NC;
    __shared__ u64 keys[CAP2];        // unsorted gathered candidates
    __shared__ u64 sorted[PRE_K];     // top-200 descending
    __shared__ u32 wsum[4];
    __shared__ u32 oflow[4];
    __shared__ float4 box[PRE_K];
    __shared__ u32 rsupA[PRE_K][8];   // per-j suppressor mask (7 words + pad)
    __shared__ u32 validw[8];
    __shared__ u32 keepw[8];
    __shared__ u64 red[256];

    u32 tid = threadIdx.x, lane = tid & 63u, wv = tid >> 6;

    // --- counts: coalesced load + wave-shfl prefix (2 barriers) ---
    u32 n_raw = cntT[(u64)bc * BLKX + tid];
    u32 m_c = n_raw < LCAP ? n_raw : (u32)LCAP;
    u32 v = m_c;
#pragma unroll
    for (u32 d = 1; d < 64u; d <<= 1) {
        u32 t = __shfl_up(v, d, 64);
        if (lane >= d) v += t;
    }
    u64 ob = __ballot(n_raw > (u32)LCAP);
    if (lane == 63u) wsum[wv] = v;
    if (lane == 0u)  oflow[wv] = (ob != 0ull) ? 1u : 0u;
    __syncthreads();
    u32 off = 0;
    for (u32 w = 0; w < wv; ++w) off += wsum[w];
    u32 inc = v + off;                       // inclusive prefix over all 256
    u32 total = wsum[0] + wsum[1] + wsum[2] + wsum[3];
    bool over = (oflow[0] | oflow[1] | oflow[2] | oflow[3]) != 0u;
    bool repaired = over || (total < (u32)PRE_K) || (total > (u32)CAP2);

    if (!repaired) {
        // --- gather ---
        u32 dst = inc - m_c;
        const u64* src = seg + ((u64)bc * BLKX + tid) * LCAP;
        for (u32 j = 0; j < m_c; ++j) keys[dst + j] = src[j];
        __syncthreads();
        // --- rank-sort: rank = #{j: key_j > key_i}; scatter rank<200 ---
        u64 ka = (tid < total) ? keys[tid] : 0ull;
        u64 kb = (tid + 256u < total) ? keys[tid + 256u] : 0ull;
        u32 ra = 0, rb = 0;
        for (u32 j = 0; j < total; ++j) {
            u64 kj = keys[j];                // broadcast read
            ra += (kj > ka) ? 1u : 0u;
            rb += (kj > kb) ? 1u : 0u;
        }
        if (tid < total && ra < (u32)PRE_K) sorted[ra] = ka;
        if (tid + 256u < total && rb < (u32)PRE_K) sorted[rb] = kb;
        __syncthreads();
    } else {
        // exact argmax-extraction top-200 (never taken for this input; exact)
        u64 cur = ~0ull;
        for (int k = 0; k < PRE_K; ++k) {
            u64 loc = 0;
            for (int a = tid; a < NA; a += 256) {
                float xx = pred[((long)b * NA + a) * NCH + 4 + c];
                float sg = sigmoid_ref(xx);
                u64 key  = ((u64)__float_as_uint(sg) << 32) | (u64)(~(u32)a);
                if (key < cur && key > loc) loc = key;
            }
            red[tid] = loc;
            __syncthreads();
            for (int s = 128; s > 0; s >>= 1) {
                if (tid < (u32)s) {
                    if (red[tid + s] > red[tid]) red[tid] = red[tid + s];
                }
                __syncthreads();
            }
            cur = red[0];
            if (tid == 0) sorted[k] = cur;
            __syncthreads();
        }
    }

    // --- decode + validity ballot (1 barrier) ---
    bool val = false;
    float4 mybox = make_float4(0.f, 0.f, 0.f, 0.f);
    float myarea = 0.f;
    if (tid < (u32)PRE_K) {
        u64 key = sorted[tid];
        float sig = __uint_as_float((u32)(key >> 32));
        int a = (int)(~(u32)key);
        if (sig > 0.05f) {  // valid = sc > CONF_THR
            float4 dd = *(const float4*)(pred + ((long)b * NA + a) * NCH);
            decode_box(dd, a, &mybox, &myarea);
            val = true;
        }
        box[tid] = mybox;
    }
    u64 vbal = __ballot(val);
    if (lane == 0u) {
        validw[2u * wv]      = (u32)vbal;
        validw[2u * wv + 1u] = (u32)(vbal >> 32);
    }
    __syncthreads();

    // --- IoU pass: per-thread register suppressor masks (broadcast reads;
    //     area recomputed from box with identical fp32 ops) ---
    u32 rsup[7];
#pragma unroll
    for (int w = 0; w < 7; ++w) {
        u32 m = 0;
        if (val && (u32)(w * 32) < tid) {
            for (int ii = 0; ii < 32; ++ii) {
                int i = w * 32 + ii;
                if ((u32)i < tid) {
                    float4 bi = box[i];
                    float ai = __fmul_rn(__fsub_rn(bi.z, bi.x), __fsub_rn(bi.w, bi.y));
                    float ltx = fmaxf(bi.x, mybox.x), lty = fmaxf(bi.y, mybox.y);
                    float rbx = fminf(bi.z, mybox.z), rby = fminf(bi.w, mybox.w);
                    float wx = fmaxf(__fsub_rn(rbx, ltx), 0.f);
                    float wy = fmaxf(__fsub_rn(rby, lty), 0.f);
                    float inter = __fmul_rn(wx, wy);
                    float den = __fadd_rn(__fsub_rn(__fadd_rn(ai, myarea), inter), 1e-8f);
                    float iou = __fdiv_rn(inter, den);
                    if (iou > 0.5f) m |= 1u << ii;
                }
            }
        }
        rsup[w] = m;   // static index (w unrolled)
    }
    if (tid < (u32)PRE_K) {
#pragma unroll
        for (int w = 0; w < 7; ++w) rsupA[tid][w] = rsup[w];
        rsupA[tid][7] = 0u;
    }
    __syncthreads();

    // --- wave-0 register Jacobi fixpoint == greedy NMS (no barriers) ---
    if (tid < 64u) {
        u32 l = tid;
        uint4 sA0 = *(const uint4*)&rsupA[l][0];
        uint4 sA1 = *(const uint4*)&rsupA[l][4];
        uint4 sB0 = *(const uint4*)&rsupA[l + 64u][0];
        uint4 sB1 = *(const uint4*)&rsupA[l + 64u][4];
        uint4 sC0 = *(const uint4*)&rsupA[l + 128u][0];
        uint4 sC1 = *(const uint4*)&rsupA[l + 128u][4];
        uint4 sD0 = make_uint4(0u, 0u, 0u, 0u);
        uint4 sD1 = make_uint4(0u, 0u, 0u, 0u);
        if (l < 8u) {
            sD0 = *(const uint4*)&rsupA[l + 192u][0];
            sD1 = *(const uint4*)&rsupA[l + 192u][4];
        }
        u32 v0 = validw[0], v1 = validw[1], v2 = validw[2], v3 = validw[3];
        u32 v4 = validw[4], v5 = validw[5], v6 = validw[6];
        u32 vb0 = (u32)(((((u64)v1 << 32) | v0) >> l) & 1ull);
        u32 vb1 = (u32)(((((u64)v3 << 32) | v2) >> l) & 1ull);
        u32 vb2 = (u32)(((((u64)v5 << 32) | v4) >> l) & 1ull);
        u32 vb3 = (l < 8u) ? ((v6 >> l) & 1u) : 0u;
        u32 k0 = v0, k1 = v1, k2 = v2, k3 = v3, k4 = v4, k5 = v5, k6 = v6;
        for (int t = 0; t < PRE_K; ++t) {
            u32 s0 = (k0 & sA0.x) | (k1 & sA0.y) | (k2 & sA0.z) | (k3 & sA0.w)
                   | (k4 & sA1.x) | (k5 & sA1.y) | (k6 & sA1.z);
            u32 s1 = (k0 & sB0.x) | (k1 & sB0.y) | (k2 & sB0.z) | (k3 & sB0.w)
                   | (k4 & sB1.x) | (k5 & sB1.y) | (k6 & sB1.z);
            u32 s2 = (k0 & sC0.x) | (k1 & sC0.y) | (k2 & sC0.z) | (k3 & sC0.w)
                   | (k4 & sC1.x) | (k5 & sC1.y) | (k6 & sC1.z);
            u32 s3 = (k0 & sD0.x) | (k1 & sD0.y) | (k2 & sD0.z) | (k3 & sD0.w)
                   | (k4 & sD1.x) | (k5 & sD1.y) | (k6 & sD1.z);
            bool n0 = vb0 && (s0 == 0u);
            bool n1 = vb1 && (s1 == 0u);
            bool n2 = vb2 && (s2 == 0u);
            bool n3 = (vb3 != 0u) && (s3 == 0u);
            u64 B0 = __ballot(n0), B1 = __ballot(n1), B2 = __ballot(n2), B3 = __ballot(n3);
            u32 nk0 = (u32)B0, nk1 = (u32)(B0 >> 32);
            u32 nk2 = (u32)B1, nk3 = (u32)(B1 >> 32);
            u32 nk4 = (u32)B2, nk5 = (u32)(B2 >> 32);
            u32 nk6 = (u32)B3;
            bool same = (nk0 == k0) && (nk1 == k1) && (nk2 == k2) && (nk3 == k3)
                     && (nk4 == k4) && (nk5 == k5) && (nk6 == k6);
            k0 = nk0; k1 = nk1; k2 = nk2; k3 = nk3; k4 = nk4; k5 = nk5; k6 = nk6;
            if (same) break;
        }
        if (l == 0u) {
            keepw[0] = k0; keepw[1] = k1; keepw[2] = k2; keepw[3] = k3;
            keepw[4] = k4; keepw[5] = k5; keepw[6] = k6;
        }
    }
    __syncthreads();

    // --- write per-class top-100 (full write incl. zeros; no memset dep) ---
    int kept = 0;
#pragma unroll
    for (int w = 0; w < 7; ++w) kept += __popc(keepw[w]);
    if (kept > MAXPC) kept = MAXPC;

    if (tid >= (u32)kept && tid < (u32)MAXPC) {
        int pos = tid;
        sc2[bc * MAXPC + pos] = 0.f;
        float* o = bb2 + ((long)bc * MAXPC + pos) * 4;
        o[0] = 0.f; o[1] = 0.f; o[2] = 0.f; o[3] = 0.f;
    }
    if (tid < (u32)PRE_K) {
        int r = tid;
        if ((keepw[r >> 5] >> (r & 31)) & 1u) {
            int pos = 0;
            for (int w = 0; w < (r >> 5); ++w) pos += __popc(keepw[w]);
            pos += __popc(keepw[r >> 5] & ((1u << (r & 31)) - 1u));
            if (pos < MAXPC) {
                u64 key = sorted[r];
                float sig = __uint_as_float((u32)(key >> 32));
                sc2[bc * MAXPC + pos] = sig;
                float* o = bb2 + ((long)bc * MAXPC + pos) * 4;
                o[0] = mybox.x; o[1] = mybox.y; o[2] = mybox.z; o[3] = mybox.w;
            }
        }
    }
}

// ---------- kernel 3: per-image final top-100, rank-select ----------

__global__ __launch_bounds__(1024) void k_final(const float* __restrict__ sc2,
                                                const float* __restrict__ bb2,
                                                float* __restrict__ out) {
    int b = blockIdx.x;
    __shared__ u32 hist[256];
    __shared__ u32 sfx[256];
    __shared__ u64 keys[CAPF];
    __shared__ u64 top[128];
    __shared__ u32 cnt_s;
    __shared__ int t_s;
    __shared__ u64 red[1024];

    for (int i = threadIdx.x; i < 256; i += blockDim.x) hist[i] = 0u;
    if (threadIdx.x < 128) top[threadIdx.x] = 0ull;
    if (threadIdx.x == 0) { cnt_s = 0u; t_s = 0; }
    __syncthreads();

    const float* s_b = sc2 + b * (NC * MAXPC);
    for (int f = threadIdx.x; f < NC * MAXPC; f += blockDim.x) {
        float s = s_b[f];
        if (s > 0.f) {
            int bin = (int)(s * 256.f); if (bin > 255) bin = 255;
            atomicAdd(&hist[bin], 1u);
        }
    }
    __syncthreads();

    // parallel suffix-sum: sfx[bin] = sum_{b'>=bin} hist[b']
    if (threadIdx.x < 256) sfx[threadIdx.x] = hist[threadIdx.x];
    __syncthreads();
    for (u32 d = 1; d < 256u; d <<= 1) {
        u32 v = 0;
        if (threadIdx.x < 256u && threadIdx.x + d < 256u) v = sfx[threadIdx.x + d];
        __syncthreads();
        if (threadIdx.x < 256u) sfx[threadIdx.x] += v;
        __syncthreads();
    }
    if (threadIdx.x < 256) {
        bool ge = sfx[threadIdx.x] >= (u32)MAXDET;
        bool nlt = (threadIdx.x == 255) || (sfx[threadIdx.x + 1] < (u32)MAXDET);
        if (ge && nlt) t_s = (int)threadIdx.x;
    }
    __syncthreads();
    int t = t_s;

    // gather candidates with bin >= t
    for (int f = threadIdx.x; f < NC * MAXPC; f += blockDim.x) {
        float s = s_b[f];
        if (s > 0.f) {
            int bin = (int)(s * 256.f); if (bin > 255) bin = 255;
            if (bin >= t) {
                u32 pos = atomicAdd(&cnt_s, 1u);
                if (pos < CAPF)
                    keys[pos] = ((u64)__float_as_uint(s) << 32) | (u64)(~(u32)f);
            }
        }
    }
    __syncthreads();
    u32 g = cnt_s;

    if (g <= (u32)CAPF) {
        // rank-select top-100 (keys unique)
        u64 ka = (threadIdx.x < g) ? keys[threadIdx.x] : 0ull;
        u64 kb = (threadIdx.x + 1024u < g) ? keys[threadIdx.x + 1024u] : 0ull;
        u32 ra = 0, rb = 0;
        for (u32 j = 0; j < g; ++j) {
            u64 kj = keys[j];                 // broadcast read
            ra += (kj > ka) ? 1u : 0u;
            rb += (kj > kb) ? 1u : 0u;
        }
        if (threadIdx.x < g && ra < (u32)MAXDET) top[ra] = ka;
        if (threadIdx.x + 1024u < g && rb < (u32)MAXDET) top[rb] = kb;
        __syncthreads();
    } else {
        // exact fallback (never for this input): 100 rounds of block argmax
        u64 cur = ~0ull;
        for (int k = 0; k < MAXDET; ++k) {
            u64 loc = 0;
            for (int f = threadIdx.x; f < NC * MAXPC; f += blockDim.x) {
                float s = s_b[f];
                if (s > 0.f) {
                    u64 key = ((u64)__float_as_uint(s) << 32) | (u64)(~(u32)f);
                    if (key < cur && key > loc) loc = key;
                }
            }
            red[threadIdx.x] = loc;
            __syncthreads();
            for (int st = 512; st > 0; st >>= 1) {
                if (threadIdx.x < (u32)st) {
                    if (red[threadIdx.x + st] > red[threadIdx.x])
                        red[threadIdx.x] = red[threadIdx.x + st];
                }
                __syncthreads();
            }
            cur = red[0];
            if (threadIdx.x == 0) top[k] = cur;
            __syncthreads();
        }
        if (threadIdx.x == 0) {
            u32 nv = 0;
            for (int r = 0; r < MAXDET; ++r) if (top[r] != 0ull) ++nv;
            cnt_s = nv;
        }
        __syncthreads();
        g = cnt_s;
    }

    if (threadIdx.x < MAXDET) {
        int r = threadIdx.x;
        u64 key = top[r];
        u32 hi = (u32)(key >> 32);
        float s = 0.f, cf = 0.f;
        float bx0 = 0.f, bx1 = 0.f, bx2 = 0.f, bx3 = 0.f;
        if (hi != 0u) {
            s = __uint_as_float(hi);
            int f = (int)(~(u32)key);
            int c = f / MAXPC, jj = f - c * MAXPC;
            const float* bsrc = bb2 + ((long)(b * NC + c) * MAXPC + jj) * 4;
            bx0 = bsrc[0]; bx1 = bsrc[1]; bx2 = bsrc[2]; bx3 = bsrc[3];
            cf = (float)c;
        }
        float* ob = out + ((long)b * MAXDET + r) * 4;
        ob[0] = bx0; ob[1] = bx1; ob[2] = bx2; ob[3] = bx3;
        out[NB * MAXDET * 4 + b * MAXDET + r] = s;
        out[NB * MAXDET * 4 + NB * MAXDET + b * MAXDET + r] = cf;
    }
    if (threadIdx.x == 0) {
        // nv = min(g, MAXDET): gathered set = all positives above t, a
        // superset of the positive top-100 (t=0 when fewer than 100 positives)
        u32 nv = g < (u32)MAXDET ? g : (u32)MAXDET;
        out[NB * MAXDET * 4 + 2 * NB * MAXDET + b] = (float)nv;
    }
}

// ---------- launcher ----------

extern "C" void kernel_launch(void* const* d_in, const int* in_sizes, int n_in,
                              void* d_out, int out_size, void* d_ws, size_t ws_size,
                              hipStream_t stream) {
    // inputs: images [8,640,640,3] (unused), predictions [8,76725,84]
    const float* pred = (const float*)d_in[1];
    if (n_in >= 2 && in_sizes[0] == NB * NA * NCH) pred = (const float*)d_in[0];

    char* ws = (char*)d_ws;
    const long BCN = (long)NB * NC;                    // 640
    u64* seg   = (u64*)ws;                             // 640*256*24*8 = 31,457,280 B
    char* p    = ws + BCN * BLKX * LCAP * 8;
    u32* cntT  = (u32*)p;            p += BCN * BLKX * 4;              // 655,360 B
    float* sc2 = (float*)p;          p += BCN * MAXPC * 4;             // 256,000 B
    float* bb2 = (float*)p;                                            // 1,024,000 B

    k_scan <<<dim3(BLKX, NB), 256, 0, stream>>>((const float4*)pred, seg, cntT);
    k_nms  <<<dim3(NB * NC),  256, 0, stream>>>(pred, seg, cntT, sc2, bb2);
    k_final<<<dim3(NB),      1024, 0, stream>>>(sc2, bb2, (float*)d_out);
}

// Round 11
// 104.106 us; speedup vs baseline: 1.3050x; 1.0640x over previous
//
#include <hip/hip_runtime.h>
#include <stdint.h>

typedef unsigned long long u64;
typedef unsigned int u32;
typedef unsigned char u8;

#define NB 8
#define NA 76725
#define NC 80
#define NCH 84
#define PRE_K 200
#define MAXPC 100
#define MAXDET 100
#define F4_PER_IMG (NA * 21u)   // 1,611,225 float4 per image

#define T0 0.93f                // exact gate: sigmoid > 0.93
#define XCUT 2.58f              // raw-logit prefilter (logit(0.93)=2.5867)
#define BLKX 256                // scan blocks per image
#define SPAN (BLKX * 256u)      // 65536 float4 per grid step
#define NSTEP 24                // 24*SPAN = 1,572,864 <= F4_PER_IMG
#define LCAP 24                 // per-(block,class) slot cap (P(overflow)~0)
#define CAP2 512                // k_nms max candidates
#define CAPF 2048               // k_final max candidates

// ---------- helpers ----------

__device__ __forceinline__ float sigmoid_ref(float x) {
    // match jax.nn.sigmoid = 1/(1+exp(-x)) in fp32 (no fast-math approx)
    return 1.0f / (1.0f + expf(-x));
}

// Decode one box exactly like the reference (fp32 ops, no fma contraction;
// anchor dims in double like the python host math, then cast to f32).
__device__ void decode_box(float4 d, int a, float4* box, float* areaOut) {
    int lvl, off, fw, stride;
    if (a < 57600)      { lvl = 0; off = 0;     fw = 80; stride = 8;   }
    else if (a < 72000) { lvl = 1; off = 57600; fw = 40; stride = 16;  }
    else if (a < 75600) { lvl = 2; off = 72000; fw = 20; stride = 32;  }
    else if (a < 76500) { lvl = 3; off = 75600; fw = 10; stride = 64;  }
    else                { lvl = 4; off = 76500; fw = 5;  stride = 128; }
    int idx  = a - off;
    int k    = idx % 9;
    int cell = idx / 9;
    int row = cell / fw, col = cell - row * fw;
    float cx = __fmul_rn((float)col + 0.5f, (float)stride);
    float cy = __fmul_rn((float)row + 0.5f, (float)stride);
    int ri = k / 3, si = k - ri * 3;
    double r    = (ri == 0) ? 0.5 : ((ri == 1) ? 1.0 : 2.0);
    double side = (double)(32 << lvl);
    double area = side * side;
    double h = sqrt(area / r);
    double w = area / h;
    double s = exp2((double)si / 3.0);
    float aw = (float)(s * w);
    float ah = (float)(s * h);
    float b0 = __fmul_rn(d.x, 0.1f);
    float b1 = __fmul_rn(d.y, 0.1f);
    float b2 = __fmul_rn(d.z, 0.2f);
    float b3 = __fmul_rn(d.w, 0.2f);
    float ux = __fadd_rn(__fmul_rn(b0, aw), cx);
    float uy = __fadd_rn(__fmul_rn(b1, ah), cy);
    float wx = __fmul_rn(expf(b2), aw);
    float wy = __fmul_rn(expf(b3), ah);
    float hx = __fmul_rn(wx, 0.5f);
    float hy = __fmul_rn(wy, 0.5f);
    float x1 = __fsub_rn(ux, hx), y1 = __fsub_rn(uy, hy);
    float x2 = __fadd_rn(ux, hx), y2 = __fadd_rn(uy, hy);
    *box = make_float4(x1, y1, x2, y2);
    *areaOut = __fmul_rn(__fsub_rn(x2, x1), __fsub_rn(y2, y1));
}

// ---------- kernel 1: streaming scan, class-major flush (no global atomics) ----------

__device__ __forceinline__ void scan4(float4 v, u32 idx,
                                      u32* lhist, u64 (*llist)[LCAP]) {
    u32 a  = idx / 21u;
    u32 c4 = idx - a * 21u;
    if (c4 == 0u) return;                        // box channels
    float m = fmaxf(fmaxf(v.x, v.y), fmaxf(v.z, v.w));
    if (m <= XCUT) return;
    u32 cb = c4 * 4u - 4u;
    float vv[4] = {v.x, v.y, v.z, v.w};
#pragma unroll
    for (int q = 0; q < 4; ++q) {
        if (vv[q] > XCUT) {
            float sig = sigmoid_ref(vv[q]);
            if (sig > T0) {
                u32 c = cb + (u32)q;
                u64 key = ((u64)__float_as_uint(sig) << 32) | (u64)(~a);
                u32 p = atomicAdd(&lhist[c], 1u);
                if (p < LCAP) llist[c][p] = key;
                // overflow (never in practice): unclamped count triggers repair
            }
        }
    }
}

__global__ __launch_bounds__(256, 4) void k_scan(const float4* __restrict__ p4,
                                                 u64* __restrict__ seg,
                                                 u32* __restrict__ cntT) {
    __shared__ u32 lhist[NC];
    __shared__ u64 llist[NC][LCAP];
    u32 b = blockIdx.y, x = blockIdx.x;
    for (u32 c = threadIdx.x; c < NC; c += 256u) lhist[c] = 0u;
    __syncthreads();

    const float4* base = p4 + (u64)b * F4_PER_IMG;
    u32 i0 = x * 256u + threadIdx.x;
#pragma unroll 1
    for (int s = 0; s < NSTEP; s += 4) {
        u32 ia = i0 + (u32)s * SPAN;
        float4 v0 = base[ia];
        float4 v1 = base[ia + SPAN];
        float4 v2 = base[ia + 2u * SPAN];
        float4 v3 = base[ia + 3u * SPAN];
        scan4(v0, ia,            lhist, llist);
        scan4(v1, ia + SPAN,     lhist, llist);
        scan4(v2, ia + 2u*SPAN,  lhist, llist);
        scan4(v3, ia + 3u*SPAN,  lhist, llist);
    }
    {
        u32 it = i0 + (u32)NSTEP * SPAN;
        if (it < F4_PER_IMG) scan4(base[it], it, lhist, llist);
    }
    __syncthreads();

    // class-major flush: block x owns slot row [ (b*NC+c)*BLKX + x ] * LCAP
    if (threadIdx.x < NC) {
        u32 c = threadIdx.x;
        u32 n = lhist[c];
        u32 m = n < LCAP ? n : (u32)LCAP;
        u64* o = seg + ((u64)(b * NC + c) * BLKX + x) * LCAP;
        for (u32 j = 0; j < m; ++j) o[j] = llist[c][j];
        cntT[(b * NC + c) * BLKX + x] = n;
    }
}

// ---------- kernel 2: gather + rank-sort + pair-IoU + wave-0 register Jacobi ----------

__global__ __launch_bounds__(512) void k_nms(const float* __restrict__ pred,
                                             const u64* __restrict__ seg,
                                             const u32* __restrict__ cntT,
                                             float* __restrict__ sc2,
                                             float* __restrict__ bb2) {
    int bc = blockIdx.x;
    int b = bc / NC, c = bc % NC;
    __shared__ u64 keys[CAP2];        // unsorted gathered candidates
    __shared__ u64 sorted[PRE_K];     // top-200 descending
    __shared__ u32 wsum[4];
    __shared__ u32 oflow[4];
    __shared__ float4 box[PRE_K];
    __shared__ u32 rsupA[PRE_K][8];   // rsupA[j][w]: suppressors i<j (7 words+pad)
    __shared__ u32 validw[8];
    __shared__ u32 keepw[8];
    __shared__ u64 red[512];

    u32 tid = threadIdx.x, lane = tid & 63u, wv = tid >> 6;

    // --- counts: threads 0-255, coalesced load + wave-shfl prefix ---
    u32 m_c = 0, incv = 0;
    if (tid < 256u) {
        u32 n_raw = cntT[(u64)bc * BLKX + tid];
        m_c = n_raw < LCAP ? n_raw : (u32)LCAP;
        u32 v = m_c;
#pragma unroll
        for (u32 d = 1; d < 64u; d <<= 1) {
            u32 t = __shfl_up(v, d, 64);
            if (lane >= d) v += t;
        }
        u64 ob = __ballot(n_raw > (u32)LCAP);
        if (lane == 63u) wsum[wv] = v;
        if (lane == 0u)  oflow[wv] = (ob != 0ull) ? 1u : 0u;
        incv = v;
    }
    __syncthreads();
    u32 total = wsum[0] + wsum[1] + wsum[2] + wsum[3];
    bool over = (oflow[0] | oflow[1] | oflow[2] | oflow[3]) != 0u;
    bool repaired = over || (total < (u32)PRE_K) || (total > (u32)CAP2);

    if (!repaired) {
        // --- gather (threads 0-255 own one scan-block row each) ---
        if (tid < 256u) {
            u32 off = 0;
            for (u32 w = 0; w < wv; ++w) off += wsum[w];
            u32 dst = incv + off - m_c;
            const u64* src = seg + ((u64)bc * BLKX + tid) * LCAP;
            for (u32 j = 0; j < m_c; ++j) keys[dst + j] = src[j];
        }
        __syncthreads();
        // --- rank-sort at width 512: rank = #{j: key_j > key_i} ---
        u64 ka = (tid < total) ? keys[tid] : 0ull;
        u32 ra = 0;
        for (u32 j = 0; j < total; ++j) {
            u64 kj = keys[j];                // broadcast read
            ra += (kj > ka) ? 1u : 0u;
        }
        if (tid < total && ra < (u32)PRE_K) sorted[ra] = ka;
        __syncthreads();
    } else {
        // exact argmax-extraction top-200 (never taken for this input; exact)
        u64 cur = ~0ull;
        for (int k = 0; k < PRE_K; ++k) {
            u64 loc = 0;
            for (int a = tid; a < NA; a += 512) {
                float xx = pred[((long)b * NA + a) * NCH + 4 + c];
                float sg = sigmoid_ref(xx);
                u64 key  = ((u64)__float_as_uint(sg) << 32) | (u64)(~(u32)a);
                if (key < cur && key > loc) loc = key;
            }
            red[tid] = loc;
            __syncthreads();
            for (int s = 256; s > 0; s >>= 1) {
                if (tid < (u32)s) {
                    if (red[tid + s] > red[tid]) red[tid] = red[tid + s];
                }
                __syncthreads();
            }
            cur = red[0];
            if (tid == 0) sorted[k] = cur;
            __syncthreads();
        }
    }

    // --- zero masks ---
    for (u32 i = tid; i < (u32)PRE_K * 8u; i += 512u) rsupA[i >> 3][i & 7u] = 0u;
    if (tid < 8u) validw[tid] = 0u;
    __syncthreads();

    // --- decode + validity ballot (threads 0-199; j<200 lives in waves 0-3) ---
    bool val = false;
    float4 mybox = make_float4(0.f, 0.f, 0.f, 0.f);
    if (tid < (u32)PRE_K) {
        u64 key = sorted[tid];
        float sig = __uint_as_float((u32)(key >> 32));
        int a = (int)(~(u32)key);
        if (sig > 0.05f) {  // valid = sc > CONF_THR
            float4 dd = *(const float4*)(pred + ((long)b * NA + a) * NCH);
            float ar;
            decode_box(dd, a, &mybox, &ar);
            val = true;
        }
        box[tid] = mybox;
    }
    u64 vbal = __ballot(val);
    if (lane == 0u && wv < 4u) {
        validw[2u * wv]      = (u32)vbal;
        validw[2u * wv + 1u] = (u32)(vbal >> 32);
    }
    __syncthreads();

    // --- pair-partitioned IoU: ~78 pair-slots/thread, atomicOr transposed ---
    // (zero boxes of invalid entries give iou = 0 -> no bit; Jacobi masks
    //  with keep ⊆ valid anyway, matching the reference exactly)
    for (u32 p = tid; p < (u32)(PRE_K * PRE_K); p += 512u) {
        u32 i  = p / (u32)PRE_K;
        u32 jx = p - i * (u32)PRE_K;
        if (jx > i) {
            float4 bi = box[i], bj = box[jx];
            float ai = __fmul_rn(__fsub_rn(bi.z, bi.x), __fsub_rn(bi.w, bi.y));
            float aj = __fmul_rn(__fsub_rn(bj.z, bj.x), __fsub_rn(bj.w, bj.y));
            float ltx = fmaxf(bi.x, bj.x), lty = fmaxf(bi.y, bj.y);
            float rbx = fminf(bi.z, bj.z), rby = fminf(bi.w, bj.w);
            float wx = fmaxf(__fsub_rn(rbx, ltx), 0.f);
            float wy = fmaxf(__fsub_rn(rby, lty), 0.f);
            float inter = __fmul_rn(wx, wy);
            float den = __fadd_rn(__fsub_rn(__fadd_rn(ai, aj), inter), 1e-8f);
            float iou = __fdiv_rn(inter, den);
            if (iou > 0.5f) atomicOr(&rsupA[jx][i >> 5], 1u << (i & 31u));
        }
    }
    __syncthreads();

    // --- wave-0 register Jacobi fixpoint == greedy NMS (no barriers) ---
    if (tid < 64u) {
        u32 l = tid;
        uint4 sA0 = *(const uint4*)&rsupA[l][0];
        uint4 sA1 = *(const uint4*)&rsupA[l][4];
        uint4 sB0 = *(const uint4*)&rsupA[l + 64u][0];
        uint4 sB1 = *(const uint4*)&rsupA[l + 64u][4];
        uint4 sC0 = *(const uint4*)&rsupA[l + 128u][0];
        uint4 sC1 = *(const uint4*)&rsupA[l + 128u][4];
        uint4 sD0 = make_uint4(0u, 0u, 0u, 0u);
        uint4 sD1 = make_uint4(0u, 0u, 0u, 0u);
        if (l < 8u) {
            sD0 = *(const uint4*)&rsupA[l + 192u][0];
            sD1 = *(const uint4*)&rsupA[l + 192u][4];
        }
        u32 v0 = validw[0], v1 = validw[1], v2 = validw[2], v3 = validw[3];
        u32 v4 = validw[4], v5 = validw[5], v6 = validw[6];
        u32 vb0 = (u32)(((((u64)v1 << 32) | v0) >> l) & 1ull);
        u32 vb1 = (u32)(((((u64)v3 << 32) | v2) >> l) & 1ull);
        u32 vb2 = (u32)(((((u64)v5 << 32) | v4) >> l) & 1ull);
        u32 vb3 = (l < 8u) ? ((v6 >> l) & 1u) : 0u;
        u32 k0 = v0, k1 = v1, k2 = v2, k3 = v3, k4 = v4, k5 = v5, k6 = v6;
        for (int t = 0; t < PRE_K; ++t) {
            u32 s0 = (k0 & sA0.x) | (k1 & sA0.y) | (k2 & sA0.z) | (k3 & sA0.w)
                   | (k4 & sA1.x) | (k5 & sA1.y) | (k6 & sA1.z);
            u32 s1 = (k0 & sB0.x) | (k1 & sB0.y) | (k2 & sB0.z) | (k3 & sB0.w)
                   | (k4 & sB1.x) | (k5 & sB1.y) | (k6 & sB1.z);
            u32 s2 = (k0 & sC0.x) | (k1 & sC0.y) | (k2 & sC0.z) | (k3 & sC0.w)
                   | (k4 & sC1.x) | (k5 & sC1.y) | (k6 & sC1.z);
            u32 s3 = (k0 & sD0.x) | (k1 & sD0.y) | (k2 & sD0.z) | (k3 & sD0.w)
                   | (k4 & sD1.x) | (k5 & sD1.y) | (k6 & sD1.z);
            bool n0 = vb0 && (s0 == 0u);
            bool n1 = vb1 && (s1 == 0u);
            bool n2 = vb2 && (s2 == 0u);
            bool n3 = (vb3 != 0u) && (s3 == 0u);
            u64 B0 = __ballot(n0), B1 = __ballot(n1), B2 = __ballot(n2), B3 = __ballot(n3);
            u32 nk0 = (u32)B0, nk1 = (u32)(B0 >> 32);
            u32 nk2 = (u32)B1, nk3 = (u32)(B1 >> 32);
            u32 nk4 = (u32)B2, nk5 = (u32)(B2 >> 32);
            u32 nk6 = (u32)B3;
            bool same = (nk0 == k0) && (nk1 == k1) && (nk2 == k2) && (nk3 == k3)
                     && (nk4 == k4) && (nk5 == k5) && (nk6 == k6);
            k0 = nk0; k1 = nk1; k2 = nk2; k3 = nk3; k4 = nk4; k5 = nk5; k6 = nk6;
            if (same) break;
        }
        if (l == 0u) {
            keepw[0] = k0; keepw[1] = k1; keepw[2] = k2; keepw[3] = k3;
            keepw[4] = k4; keepw[5] = k5; keepw[6] = k6;
        }
    }
    __syncthreads();

    // --- write per-class top-100 (full write incl. zeros; no memset dep) ---
    int kept = 0;
#pragma unroll
    for (int w = 0; w < 7; ++w) kept += __popc(keepw[w]);
    if (kept > MAXPC) kept = MAXPC;

    if (tid >= (u32)kept && tid < (u32)MAXPC) {
        int pos = tid;
        sc2[bc * MAXPC + pos] = 0.f;
        float* o = bb2 + ((long)bc * MAXPC + pos) * 4;
        o[0] = 0.f; o[1] = 0.f; o[2] = 0.f; o[3] = 0.f;
    }
    if (tid < (u32)PRE_K) {
        int r = tid;
        if ((keepw[r >> 5] >> (r & 31)) & 1u) {
            int pos = 0;
            for (int w = 0; w < (r >> 5); ++w) pos += __popc(keepw[w]);
            pos += __popc(keepw[r >> 5] & ((1u << (r & 31)) - 1u));
            if (pos < MAXPC) {
                u64 key = sorted[r];
                float sig = __uint_as_float((u32)(key >> 32));
                sc2[bc * MAXPC + pos] = sig;
                float* o = bb2 + ((long)bc * MAXPC + pos) * 4;
                o[0] = mybox.x; o[1] = mybox.y; o[2] = mybox.z; o[3] = mybox.w;
            }
        }
    }
}

// ---------- kernel 3: per-image final top-100, rank-select ----------

__global__ __launch_bounds__(1024) void k_final(const float* __restrict__ sc2,
                                                const float* __restrict__ bb2,
                                                float* __restrict__ out) {
    int b = blockIdx.x;
    __shared__ u32 hist[256];
    __shared__ u32 sfx[256];
    __shared__ u64 keys[CAPF];
    __shared__ u64 top[128];
    __shared__ u32 cnt_s;
    __shared__ int t_s;
    __shared__ u64 red[1024];

    for (int i = threadIdx.x; i < 256; i += blockDim.x) hist[i] = 0u;
    if (threadIdx.x < 128) top[threadIdx.x] = 0ull;
    if (threadIdx.x == 0) { cnt_s = 0u; t_s = 0; }
    __syncthreads();

    const float* s_b = sc2 + b * (NC * MAXPC);
    for (int f = threadIdx.x; f < NC * MAXPC; f += blockDim.x) {
        float s = s_b[f];
        if (s > 0.f) {
            int bin = (int)(s * 256.f); if (bin > 255) bin = 255;
            atomicAdd(&hist[bin], 1u);
        }
    }
    __syncthreads();

    // parallel suffix-sum: sfx[bin] = sum_{b'>=bin} hist[b']
    if (threadIdx.x < 256) sfx[threadIdx.x] = hist[threadIdx.x];
    __syncthreads();
    for (u32 d = 1; d < 256u; d <<= 1) {
        u32 v = 0;
        if (threadIdx.x < 256u && threadIdx.x + d < 256u) v = sfx[threadIdx.x + d];
        __syncthreads();
        if (threadIdx.x < 256u) sfx[threadIdx.x] += v;
        __syncthreads();
    }
    if (threadIdx.x < 256) {
        bool ge = sfx[threadIdx.x] >= (u32)MAXDET;
        bool nlt = (threadIdx.x == 255) || (sfx[threadIdx.x + 1] < (u32)MAXDET);
        if (ge && nlt) t_s = (int)threadIdx.x;
    }
    __syncthreads();
    int t = t_s;

    // gather candidates with bin >= t
    for (int f = threadIdx.x; f < NC * MAXPC; f += blockDim.x) {
        float s = s_b[f];
        if (s > 0.f) {
            int bin = (int)(s * 256.f); if (bin > 255) bin = 255;
            if (bin >= t) {
                u32 pos = atomicAdd(&cnt_s, 1u);
                if (pos < CAPF)
                    keys[pos] = ((u64)__float_as_uint(s) << 32) | (u64)(~(u32)f);
            }
        }
    }
    __syncthreads();
    u32 g = cnt_s;

    if (g <= (u32)CAPF) {
        // rank-select top-100 (keys unique)
        u64 ka = (threadIdx.x < g) ? keys[threadIdx.x] : 0ull;
        u64 kb = (threadIdx.x + 1024u < g) ? keys[threadIdx.x + 1024u] : 0ull;
        u32 ra = 0, rb = 0;
        for (u32 j = 0; j < g; ++j) {
            u64 kj = keys[j];                 // broadcast read
            ra += (kj > ka) ? 1u : 0u;
            rb += (kj > kb) ? 1u : 0u;
        }
        if (threadIdx.x < g && ra < (u32)MAXDET) top[ra] = ka;
        if (threadIdx.x + 1024u < g && rb < (u32)MAXDET) top[rb] = kb;
        __syncthreads();
    } else {
        // exact fallback (never for this input): 100 rounds of block argmax
        u64 cur = ~0ull;
        for (int k = 0; k < MAXDET; ++k) {
            u64 loc = 0;
            for (int f = threadIdx.x; f < NC * MAXPC; f += blockDim.x) {
                float s = s_b[f];
                if (s > 0.f) {
                    u64 key = ((u64)__float_as_uint(s) << 32) | (u64)(~(u32)f);
                    if (key < cur && key > loc) loc = key;
                }
            }
            red[threadIdx.x] = loc;
            __syncthreads();
            for (int st = 512; st > 0; st >>= 1) {
                if (threadIdx.x < (u32)st) {
                    if (red[threadIdx.x + st] > red[threadIdx.x])
                        red[threadIdx.x] = red[threadIdx.x + st];
                }
                __syncthreads();
            }
            cur = red[0];
            if (threadIdx.x == 0) top[k] = cur;
            __syncthreads();
        }
        if (threadIdx.x == 0) {
            u32 nv = 0;
            for (int r = 0; r < MAXDET; ++r) if (top[r] != 0ull) ++nv;
            cnt_s = nv;
        }
        __syncthreads();
        g = cnt_s;
    }

    if (threadIdx.x < MAXDET) {
        int r = threadIdx.x;
        u64 key = top[r];
        u32 hi = (u32)(key >> 32);
        float s = 0.f, cf = 0.f;
        float bx0 = 0.f, bx1 = 0.f, bx2 = 0.f, bx3 = 0.f;
        if (hi != 0u) {
            s = __uint_as_float(hi);
            int f = (int)(~(u32)key);
            int c = f / MAXPC, jj = f - c * MAXPC;
            const float* bsrc = bb2 + ((long)(b * NC + c) * MAXPC + jj) * 4;
            bx0 = bsrc[0]; bx1 = bsrc[1]; bx2 = bsrc[2]; bx3 = bsrc[3];
            cf = (float)c;
        }
        float* ob = out + ((long)b * MAXDET + r) * 4;
        ob[0] = bx0; ob[1] = bx1; ob[2] = bx2; ob[3] = bx3;
        out[NB * MAXDET * 4 + b * MAXDET + r] = s;
        out[NB * MAXDET * 4 + NB * MAXDET + b * MAXDET + r] = cf;
    }
    if (threadIdx.x == 0) {
        // nv = min(g, MAXDET): gathered set = all positives above t, a
        // superset of the positive top-100 (t=0 when fewer than 100 positives)
        u32 nv = g < (u32)MAXDET ? g : (u32)MAXDET;
        out[NB * MAXDET * 4 + 2 * NB * MAXDET + b] = (float)nv;
    }
}

// ---------- launcher ----------

extern "C" void kernel_launch(void* const* d_in, const int* in_sizes, int n_in,
                              void* d_out, int out_size, void* d_ws, size_t ws_size,
                              hipStream_t stream) {
    // inputs: images [8,640,640,3] (unused), predictions [8,76725,84]
    const float* pred = (const float*)d_in[1];
    if (n_in >= 2 && in_sizes[0] == NB * NA * NCH) pred = (const float*)d_in[0];

    char* ws = (char*)d_ws;
    const long BCN = (long)NB * NC;                    // 640
    u64* seg   = (u64*)ws;                             // 640*256*24*8 = 31,457,280 B
    char* p    = ws + BCN * BLKX * LCAP * 8;
    u32* cntT  = (u32*)p;            p += BCN * BLKX * 4;              // 655,360 B
    float* sc2 = (float*)p;          p += BCN * MAXPC * 4;             // 256,000 B
    float* bb2 = (float*)p;                                            // 1,024,000 B

    k_scan <<<dim3(BLKX, NB), 256, 0, stream>>>((const float4*)pred, seg, cntT);
    k_nms  <<<dim3(NB * NC),  512, 0, stream>>>(pred, seg, cntT, sc2, bb2);
    k_final<<<dim3(NB),      1024, 0, stream>>>(sc2, bb2, (float*)d_out);
}